// Round 4
// baseline (670.780 us; speedup 1.0000x reference)
//
#include <hip/hip_runtime.h>

#define DEV static __device__ __forceinline__

typedef unsigned short u16;
typedef __attribute__((ext_vector_type(8))) short bf16x8;     // 8 bf16 in 4 VGPRs
typedef __attribute__((ext_vector_type(8))) unsigned short u16x8;
typedef __attribute__((ext_vector_type(4))) unsigned short u16x4;
typedef __attribute__((ext_vector_type(4))) float f32x4;

static constexpr int Bb = 4, Ss = 2048, Dd = 1024, Hh = 16, DFF = 4096;
static constexpr int BS = Bb * Ss;  // 8192 rows
// 1/sqrt(64) * log2(e): QK^T then exp2 == exp(S/8)
#define QSCALE 0.18033688011112042f

DEV u16 f2bf(float f) {
  union { float f; unsigned u; } x; x.f = f;
  unsigned r = x.u + 0x7fffu + ((x.u >> 16) & 1u);  // RNE
  return (u16)(r >> 16);
}

DEV unsigned cvtpk(float lo, float hi) {  // 2xf32 -> packed 2xbf16 (lo->[15:0])
  unsigned r;
  asm("v_cvt_pk_bf16_f32 %0, %1, %2" : "=v"(r) : "v"(lo), "v"(hi));
  return r;
}

DEV void gload_lds16(const void* g, void* l) {
  __builtin_amdgcn_global_load_lds(
      (const __attribute__((address_space(1))) unsigned int*)g,
      (__attribute__((address_space(3))) unsigned int*)l, 16, 0, 0);
}

DEV unsigned lds_addr(const void* p) {
  return (unsigned)(size_t)(const __attribute__((address_space(3))) void*)p;
}

DEV f32x4 mfma16(bf16x8 a, bf16x8 b, f32x4 c) {
  return __builtin_amdgcn_mfma_f32_16x16x32_bf16(a, b, c, 0, 0, 0);
}

DEV bf16x8 cat8(u16x4 a, u16x4 b) {
  bf16x8 v;
#pragma unroll
  for (int j = 0; j < 4; j++) { v[j] = (short)a[j]; v[j + 4] = (short)b[j]; }
  return v;
}

#define TRRD(dst, addr, OFF)                                     \
  asm volatile("ds_read_b64_tr_b16 %0, %1 offset:" #OFF         \
               : "=v"(dst) : "v"(addr))

// ---------------- elementwise cast fp32 -> bf16 ----------------
__global__ void cast_src_k(const float* __restrict__ in, u16* __restrict__ outp, int n) {
  int i = (blockIdx.x * 256 + threadIdx.x) * 4;
  const int stride = gridDim.x * 256 * 4;
  for (; i < n; i += stride) {
    float4 v = *(const float4*)(in + i);
    u16x4 o; o[0] = f2bf(v.x); o[1] = f2bf(v.y); o[2] = f2bf(v.z); o[3] = f2bf(v.w);
    *(u16x4*)(outp + i) = o;
  }
}

// ---------------- transpose + cast: W (KxN f32) -> Wt (NxK bf16) ----------------
__global__ __launch_bounds__(256) void transpose_cast(const float* __restrict__ W,
                                                      u16* __restrict__ Wt, int K, int N) {
  __shared__ float t[32][33];
  const int n0 = blockIdx.x * 32, k0 = blockIdx.y * 32;
  const int tx = threadIdx.x & 31, ty = threadIdx.x >> 5;
#pragma unroll
  for (int i = 0; i < 4; i++) t[ty + i * 8][tx] = W[(size_t)(k0 + ty + i * 8) * N + n0 + tx];
  __syncthreads();
#pragma unroll
  for (int i = 0; i < 4; i++) Wt[(size_t)(n0 + ty + i * 8) * K + k0 + tx] = f2bf(t[tx][ty + i * 8]);
}

// ---------------- mask summary ----------------
__global__ void mask_init_k(int* flags) { if (threadIdx.x < 4) flags[threadIdx.x] = 1; }
__global__ void mask_check_k(const int* __restrict__ mask, int* __restrict__ flags, int n) {
  int i = blockIdx.x * 256 + threadIdx.x;
  const int st = gridDim.x * 256;
  for (; i < n; i += st) if (mask[i] == 0) flags[i >> 22] = 0;  // S*S = 2^22
}

// ---------------- 256^2 8-phase GEMM (T2+T3+T4+T5) ----------------
// 512 thr = 8 waves (2M x 4N), BM=BN=256, BK=64, per-wave C = 128x64, LDS 128 KiB.
template <int MODE>
__global__ __launch_bounds__(512, 2) void gemm8p(const u16* __restrict__ A,
                                                 const u16* __restrict__ Bt,
                                                 const float* __restrict__ bias,
                                                 void* __restrict__ C,
                                                 int M, int N, int K) {
  __shared__ alignas(128) u16 lds[65536];
  const int tid = threadIdx.x, lane = tid & 63, w = tid >> 6;
  const int wm = w >> 2, wc = w & 3;
  const int frow = lane & 15, hi = lane >> 4;
  const int bm = blockIdx.y * 256, bn = blockIdx.x * 256;
  const int NT = K >> 6;

  const int cs = ((tid & 7) ^ ((tid >> 3) & 7)) * 8;
  const int sr = w * 8 + ((lane >> 3) & 7);
  const u16* Ab = A + (size_t)(bm + sr) * K + cs;
  const u16* Bbp = Bt + (size_t)(bn + sr) * K + cs;
  u16* lw = lds + w * 512;

  const int c0 = (hi * 8) ^ ((frow & 7) << 3);
  const u16* Abase = lds + wm * 8192 + frow * 64;
  const u16* Bbase = lds + 32768 + (wc >> 1) * 8192 + (wc & 1) * 4096 + frow * 64;

  f32x4 acc[8][4] = {};
  bf16x8 af0[4][2], af1[4][2], bf0[2][2], bf1[2][2];

#define STG(Pb, hh, kk, reg)                                                     \
  do {                                                                           \
    gload_lds16((Pb) + (size_t)((hh) * 128) * K + (kk), lw + (reg));             \
    gload_lds16((Pb) + (size_t)((hh) * 128 + 64) * K + (kk), lw + (reg) + 4096); \
  } while (0)
#define LDA(dst, sb, mh)                                                              \
  do {                                                                                \
    _Pragma("unroll") for (int m = 0; m < 4; m++) {                                   \
      dst[m][0] = *(const bf16x8*)(Abase + (sb) + ((mh) * 4 + m) * 1024 + c0);        \
      dst[m][1] = *(const bf16x8*)(Abase + (sb) + ((mh) * 4 + m) * 1024 + (c0 ^ 32)); \
    }                                                                                 \
  } while (0)
#define LDB(dst, sb, nh)                                                              \
  do {                                                                                \
    _Pragma("unroll") for (int n = 0; n < 2; n++) {                                   \
      dst[n][0] = *(const bf16x8*)(Bbase + (sb) + ((nh) * 2 + n) * 1024 + c0);        \
      dst[n][1] = *(const bf16x8*)(Bbase + (sb) + ((nh) * 2 + n) * 1024 + (c0 ^ 32)); \
    }                                                                                 \
  } while (0)
#define MM(AF, BF, mh, nh)                                                             \
  do {                                                                                 \
    __builtin_amdgcn_s_setprio(1);                                                     \
    _Pragma("unroll") for (int m = 0; m < 4; m++) _Pragma("unroll") for (int n = 0;    \
                                                                        n < 2; n++) { \
      acc[(mh)*4+m][(nh)*2+n] = mfma16(AF[m][0], BF[n][0], acc[(mh)*4+m][(nh)*2+n]);   \
      acc[(mh)*4+m][(nh)*2+n] = mfma16(AF[m][1], BF[n][1], acc[(mh)*4+m][(nh)*2+n]);   \
    }                                                                                  \
    __builtin_amdgcn_s_setprio(0);                                                     \
  } while (0)
#define BAR asm volatile("s_barrier" ::: "memory")
#define VMC(n) asm volatile("s_waitcnt vmcnt(" #n ")" ::: "memory")

  STG(Ab, 0, 0, 0);        STG(Ab, 1, 0, 8192);
  STG(Bbp, 0, 0, 32768);   STG(Bbp, 1, 0, 40960);
  STG(Ab, 0, 64, 16384);   STG(Ab, 1, 64, 24576);
  VMC(0);
  BAR;

  const int NI = NT >> 1;
#pragma unroll 1
  for (int i = 0; i < NI; ++i) {
    const int T = i * 2;
    const int kT1 = (T + 1) << 6;
    const int kT2 = (T + 2 < NT ? T + 2 : NT - 1) << 6;
    const int kT3 = (T + 3 < NT ? T + 3 : NT - 1) << 6;
    LDA(af0, 0, 0); LDB(bf0, 0, 0);
    STG(Bbp, 0, kT1, 49152);
    BAR; MM(af0, bf0, 0, 0); BAR;
    LDA(af1, 0, 1);
    STG(Bbp, 1, kT1, 57344);
    BAR; MM(af1, bf0, 1, 0); BAR;
    LDB(bf1, 0, 1);
    STG(Ab, 0, kT2, 0);
    BAR; MM(af0, bf1, 0, 1); BAR;
    STG(Ab, 1, kT2, 8192);
    VMC(4); BAR; MM(af1, bf1, 1, 1); BAR;
    LDA(af0, 16384, 0); LDB(bf0, 16384, 0);
    STG(Bbp, 0, kT2, 32768);
    BAR; MM(af0, bf0, 0, 0); BAR;
    LDA(af1, 16384, 1);
    STG(Bbp, 1, kT2, 40960);
    BAR; MM(af1, bf0, 1, 0); BAR;
    LDB(bf1, 16384, 1);
    STG(Ab, 0, kT3, 16384);
    BAR; MM(af0, bf1, 0, 1); BAR;
    STG(Ab, 1, kT3, 24576);
    VMC(4); BAR; MM(af1, bf1, 1, 1); BAR;
  }

#undef STG
#undef LDA
#undef LDB
#undef MM
#undef BAR
#undef VMC

#pragma unroll
  for (int m = 0; m < 8; m++) {
#pragma unroll
    for (int n = 0; n < 4; n++) {
      const int col = bn + wc * 64 + n * 16 + frow;
      const float bv = (MODE == 2) ? bias[col] : 0.f;
      const float sc = (MODE == 3 && col < Dd) ? QSCALE : 1.f;
#pragma unroll
      for (int r = 0; r < 4; r++) {
        const int row = bm + wm * 128 + m * 16 + hi * 4 + r;
        float v = acc[m][n][r];
        if (MODE == 2) v = fmaxf(v + bv, 0.f);
        if (MODE == 3) v *= sc;
        if (MODE == 0) ((float*)C)[(size_t)row * N + col] = v;
        else           ((u16*)C)[(size_t)row * N + col] = f2bf(v);
      }
    }
  }
}

// ---------------- 128x256 8-phase GEMM (grid-balance variant, 96 KiB LDS) ----------
// 512 thr = 8 waves (2M x 4N), BM=128, BN=256, BK=64, per-wave C = 64x64.
// LDS (u16): A slots [0,8192),[8192,16384) layout [128r][64k];
//            B slots [16384,32768),[32768,49152) layout [256r][64k].
// Reads XOR-swizzled elem ^= (row&7)<<3; staging source pre-swizzled (both-sides).
// Ring per 2 K-tiles: ph1 B'h0, ph2 B'h1, ph3 A''(both), ph4 vmcnt(2);
// ph5-8 mirror on other slot. Counted vmcnt never 0 in-loop.
template <int MODE>
__global__ __launch_bounds__(512, 2) void gemm8ph(const u16* __restrict__ A,
                                                  const u16* __restrict__ Bt,
                                                  const float* __restrict__ bias,
                                                  void* __restrict__ C,
                                                  int M, int N, int K) {
  __shared__ alignas(128) u16 lds[49152];
  const int tid = threadIdx.x, lane = tid & 63, w = tid >> 6;
  const int wm = w >> 2, wc = w & 3;
  const int frow = lane & 15, hi = lane >> 4;
  const int bm = blockIdx.y * 128, bn = blockIdx.x * 256;
  const int NT = K >> 6;

  const int cs = ((tid & 7) ^ ((tid >> 3) & 7)) * 8;
  const int sr = w * 8 + ((lane >> 3) & 7);
  const u16* Ab = A + (size_t)(bm + sr) * K + cs;
  const u16* Bbp = Bt + (size_t)(bn + sr) * K + cs;
  u16* lwA = lds + w * 512;
  u16* lwB = lds + 16384 + w * 512;

  const int c0 = (hi * 8) ^ ((frow & 7) << 3);
  const u16* Abase = lds + wm * 4096 + frow * 64;
  const u16* Bbase = lds + 16384 + wc * 4096 + frow * 64;

  f32x4 acc[4][4] = {};
  bf16x8 af0[2][2], af1[2][2], bf0[2][2], bf1[2][2];

#define STGA(kk, reg)                                              \
  do {                                                             \
    gload_lds16(Ab + (kk), lwA + (reg));                           \
    gload_lds16(Ab + (size_t)64 * K + (kk), lwA + (reg) + 4096);   \
  } while (0)
#define STGB(hh, kk, reg)                                                            \
  do {                                                                               \
    gload_lds16(Bbp + (size_t)((hh) * 128) * K + (kk), lwB + (reg) + (hh) * 8192);   \
    gload_lds16(Bbp + (size_t)((hh) * 128 + 64) * K + (kk),                          \
                lwB + (reg) + (hh) * 8192 + 4096);                                   \
  } while (0)
#define LDA2(dst, sb, mh)                                                             \
  do {                                                                                \
    _Pragma("unroll") for (int m = 0; m < 2; m++) {                                   \
      dst[m][0] = *(const bf16x8*)(Abase + (sb) + ((mh) * 2 + m) * 1024 + c0);        \
      dst[m][1] = *(const bf16x8*)(Abase + (sb) + ((mh) * 2 + m) * 1024 + (c0 ^ 32)); \
    }                                                                                 \
  } while (0)
#define LDB2(dst, sb, nh)                                                             \
  do {                                                                                \
    _Pragma("unroll") for (int n = 0; n < 2; n++) {                                   \
      dst[n][0] = *(const bf16x8*)(Bbase + (sb) + ((nh) * 2 + n) * 1024 + c0);        \
      dst[n][1] = *(const bf16x8*)(Bbase + (sb) + ((nh) * 2 + n) * 1024 + (c0 ^ 32)); \
    }                                                                                 \
  } while (0)
#define MM2(AF, BF, mh, nh)                                                            \
  do {                                                                                 \
    __builtin_amdgcn_s_setprio(1);                                                     \
    _Pragma("unroll") for (int m = 0; m < 2; m++) _Pragma("unroll") for (int n = 0;    \
                                                                        n < 2; n++) { \
      acc[(mh)*2+m][(nh)*2+n] = mfma16(AF[m][0], BF[n][0], acc[(mh)*2+m][(nh)*2+n]);   \
      acc[(mh)*2+m][(nh)*2+n] = mfma16(AF[m][1], BF[n][1], acc[(mh)*2+m][(nh)*2+n]);   \
    }                                                                                  \
    __builtin_amdgcn_s_setprio(0);                                                     \
  } while (0)
#define BAR asm volatile("s_barrier" ::: "memory")
#define VMC(n) asm volatile("s_waitcnt vmcnt(" #n ")" ::: "memory")

  // prologue: A(0)->Aslot0, B(0)->Bslot0, A(1)->Aslot1
  STGA(0, 0);
  STGB(0, 0, 0); STGB(1, 0, 0);
  STGA(64, 8192);
  VMC(0);
  BAR;

  const int NI = NT >> 1;
#pragma unroll 1
  for (int i = 0; i < NI; ++i) {
    const int T = i * 2;
    const int kT1 = (T + 1) << 6;
    const int kT2 = (T + 2 < NT ? T + 2 : NT - 1) << 6;
    const int kT3 = (T + 3 < NT ? T + 3 : NT - 1) << 6;
    // ph1: read slot0 A m0-1 + B n0-1; stage B(T+1)h0 -> Bslot1
    LDA2(af0, 0, 0); LDB2(bf0, 0, 0);
    STGB(0, kT1, 16384);
    BAR; MM2(af0, bf0, 0, 0); BAR;
    // ph2: read A m2-3; stage B(T+1)h1
    LDA2(af1, 0, 1);
    STGB(1, kT1, 16384);
    BAR; MM2(af1, bf0, 1, 0); BAR;
    // ph3: read B n2-3; stage A(T+2) -> Aslot0
    LDB2(bf1, 0, 1);
    STGA(kT2, 0);
    BAR; MM2(af0, bf1, 0, 1); BAR;
    // ph4: vmcnt(2) [A(T+2) outstanding; B(T+1) landed]
    VMC(2); BAR; MM2(af1, bf1, 1, 1); BAR;
    // ph5: read slot1; stage B(T+2)h0 -> Bslot0
    LDA2(af0, 8192, 0); LDB2(bf0, 16384, 0);
    STGB(0, kT2, 0);
    BAR; MM2(af0, bf0, 0, 0); BAR;
    // ph6: stage B(T+2)h1
    LDA2(af1, 8192, 1);
    STGB(1, kT2, 0);
    BAR; MM2(af1, bf0, 1, 0); BAR;
    // ph7: stage A(T+3) -> Aslot1
    LDB2(bf1, 16384, 1);
    STGA(kT3, 8192);
    BAR; MM2(af0, bf1, 0, 1); BAR;
    // ph8: vmcnt(2) [A(T+3) outstanding; B(T+2), A(T+2) landed]
    VMC(2); BAR; MM2(af1, bf1, 1, 1); BAR;
  }

#undef STGA
#undef STGB
#undef LDA2
#undef LDB2
#undef MM2
#undef BAR
#undef VMC

#pragma unroll
  for (int m = 0; m < 4; m++) {
#pragma unroll
    for (int n = 0; n < 4; n++) {
      const int col = bn + wc * 64 + n * 16 + frow;
      const float bv = (MODE == 2) ? bias[col] : 0.f;
      const float sc = (MODE == 3 && col < Dd) ? QSCALE : 1.f;
#pragma unroll
      for (int r = 0; r < 4; r++) {
        const int row = bm + wm * 64 + m * 16 + hi * 4 + r;
        float v = acc[m][n][r];
        if (MODE == 2) v = fmaxf(v + bv, 0.f);
        if (MODE == 3) v *= sc;
        if (MODE == 0) ((float*)C)[(size_t)row * N + col] = v;
        else           ((u16*)C)[(size_t)row * N + col] = f2bf(v);
      }
    }
  }
}

// ---------------- fused flash attention ----------------
// qkv rows = [Q*QSCALE | K | V]; softmax in exp2 domain; defer-max (THR=8);
// packed cvt_pk P-writes; tr-read V; 2-phase dbuf staging.
__global__ __launch_bounds__(256, 3) void attn_fwd(const u16* __restrict__ qkv,
                                                   const int* __restrict__ mask,
                                                   const int* __restrict__ mflag,
                                                   u16* __restrict__ outb) {
  __shared__ alignas(128) u16 Ks[2 * 4096];
  __shared__ alignas(128) u16 Vs[2 * 4096];
  __shared__ alignas(16)  u16 Pl[4 * 16 * 72];

  const int bx = blockIdx.x;
  const int qt = bx & 31;
  const int h = (bx >> 5) & 15;
  const int b = bx >> 9;
  const int tid = threadIdx.x;
  const int lane = tid & 63;
  const int w = tid >> 6;
  const int frow = lane & 15, hi = lane >> 4;
  const int qbase = qt * 64 + w * 16;

  bf16x8 qf[2];
  {
    const u16* qp = qkv + (size_t)(b * Ss + qbase + frow) * 3072 + h * 64 + hi * 8;
    qf[0] = *(const bf16x8*)(qp);
    qf[1] = *(const bf16x8*)(qp + 32);
  }
  const int allones = mflag[b];
  u16* Plw = Pl + w * (16 * 72);

  f32x4 oacc[4] = {};
  float mrow = -1e30f, lrow = 0.f;

  const size_t kvb = (size_t)(b * Ss) * 3072 + 1024 + h * 64;
  const int kcol_s = tid >> 2;
  const int dsw = ((tid & 3) ^ (kcol_s & 3)) * 8;
  const u16* Kg0 = qkv + kvb + (size_t)kcol_s * 3072 + dsw;
  const u16* Kg1 = Kg0 + 32;
  int kV0, dkV0, kV1, dkV1;
  {
    int p = tid, T = p >> 3, j = (p >> 1) & 3, hh = p & 1;
    kV0 = ((T >> 3) & 1) * 32 + (T & 3) * 8 + ((T >> 2) & 1) * 4 + j;
    dkV0 = ((T >> 4) & 3) * 16 + hh * 8;
    p = tid + 256; T = p >> 3; j = (p >> 1) & 3; hh = p & 1;
    kV1 = ((T >> 3) & 1) * 32 + (T & 3) * 8 + ((T >> 2) & 1) * 4 + j;
    dkV1 = ((T >> 4) & 3) * 16 + hh * 8;
  }
  const u16* Vg0 = qkv + kvb + 1024 + (size_t)kV0 * 3072 + dkV0;
  const u16* Vg1 = qkv + kvb + 1024 + (size_t)kV1 * 3072 + dkV1;

  const unsigned vbase = lds_addr(Vs) + lane * 8;

  gload_lds16(Kg0, Ks + w * 512);
  gload_lds16(Kg1, Ks + 2048 + w * 512);
  gload_lds16(Vg0, Vs + w * 512);
  gload_lds16(Vg1, Vs + 2048 + w * 512);
  __syncthreads();

#pragma unroll 1
  for (int kt = 0; kt < 32; kt++) {
    const int cur = kt & 1;
    if (kt < 31) {
      const size_t soff = (size_t)(kt + 1) * 64 * 3072;
      u16* Kb = Ks + (cur ^ 1) * 4096;
      u16* Vb = Vs + (cur ^ 1) * 4096;
      gload_lds16(Kg0 + soff, Kb + w * 512);
      gload_lds16(Kg1 + soff, Kb + 2048 + w * 512);
      gload_lds16(Vg0 + soff, Vb + w * 512);
      gload_lds16(Vg1 + soff, Vb + 2048 + w * 512);
    }
    const u16* Kbuf = Ks + cur * 4096;

    f32x4 sacc[4] = {};
    const int kswz = (hi ^ (frow & 3)) * 8;
#pragma unroll
    for (int ks = 0; ks < 2; ks++)
#pragma unroll
      for (int n = 0; n < 4; n++) {
        bf16x8 kf = *(const bf16x8*)&Kbuf[ks * 2048 + (n * 16 + frow) * 32 + kswz];
        sacc[n] = mfma16(kf, qf[ks], sacc[n]);
      }

    const int srow = kt * 64;
    float sv[16];
#pragma unroll
    for (int n = 0; n < 4; n++)
#pragma unroll
      for (int r = 0; r < 4; r++) {
        float s = sacc[n][r];  // already in log2 units (QSCALE folded)
        if (!allones) {
          const int qq = b * Ss + qbase + frow;
          const int kk = srow + n * 16 + hi * 4 + r;
          if (mask[(size_t)qq * Ss + kk] == 0) s = -1e30f;
        }
        sv[n * 4 + r] = s;
      }
    float mt = sv[0];
#pragma unroll
    for (int i = 1; i < 16; i++) mt = fmaxf(mt, sv[i]);
    mt = fmaxf(mt, __shfl_xor(mt, 16));
    mt = fmaxf(mt, __shfl_xor(mt, 32));
    // defer-max (T13): only rescale when the running max grew by > 8 (exp2 units)
    if (__any(mt > mrow + 8.f)) {
      const float mn = fmaxf(mrow, mt);
      const float al = exp2f(mrow - mn);
      mrow = mn;
      lrow *= al;
      float alr[4];
#pragma unroll
      for (int r = 0; r < 4; r++) alr[r] = __shfl(al, (lane & 48) | (hi * 4 + r));
#pragma unroll
      for (int n = 0; n < 4; n++) {
        oacc[n][0] *= alr[0]; oacc[n][1] *= alr[1];
        oacc[n][2] *= alr[2]; oacc[n][3] *= alr[3];
      }
    }
    float ps[16], rs = 0.f;
#pragma unroll
    for (int i = 0; i < 16; i++) { ps[i] = exp2f(sv[i] - mrow); rs += ps[i]; }
    rs += __shfl_xor(rs, 16);
    rs += __shfl_xor(rs, 32);
    lrow += rs;
    // packed P write: 8 cvt_pk + 8 ds_write_b32
#pragma unroll
    for (int n = 0; n < 4; n++) {
      *(unsigned*)(Plw + frow * 72 + n * 16 + hi * 4)     = cvtpk(ps[n * 4 + 0], ps[n * 4 + 1]);
      *(unsigned*)(Plw + frow * 72 + n * 16 + hi * 4 + 2) = cvtpk(ps[n * 4 + 2], ps[n * 4 + 3]);
    }

    const unsigned vaddr = vbase + (cur << 13);
    u16x4 t0, t1, t2, t3, t4, t5, t6, t7;
    TRRD(t0, vaddr, 0);    TRRD(t1, vaddr, 512);
    TRRD(t2, vaddr, 2048); TRRD(t3, vaddr, 2560);
    TRRD(t4, vaddr, 4096); TRRD(t5, vaddr, 4608);
    TRRD(t6, vaddr, 6144); TRRD(t7, vaddr, 6656);
    {
      bf16x8 pa = *(const bf16x8*)&Plw[frow * 72 + hi * 8];
      asm volatile("s_waitcnt lgkmcnt(0)" ::: "memory");
      __builtin_amdgcn_sched_barrier(0);
      oacc[0] = mfma16(pa, cat8(t0, t1), oacc[0]);
      oacc[1] = mfma16(pa, cat8(t2, t3), oacc[1]);
      oacc[2] = mfma16(pa, cat8(t4, t5), oacc[2]);
      oacc[3] = mfma16(pa, cat8(t6, t7), oacc[3]);
    }
    TRRD(t0, vaddr, 1024); TRRD(t1, vaddr, 1536);
    TRRD(t2, vaddr, 3072); TRRD(t3, vaddr, 3584);
    TRRD(t4, vaddr, 5120); TRRD(t5, vaddr, 5632);
    TRRD(t6, vaddr, 7168); TRRD(t7, vaddr, 7680);
    {
      bf16x8 pa = *(const bf16x8*)&Plw[frow * 72 + 32 + hi * 8];
      asm volatile("s_waitcnt lgkmcnt(0)" ::: "memory");
      __builtin_amdgcn_sched_barrier(0);
      oacc[0] = mfma16(pa, cat8(t0, t1), oacc[0]);
      oacc[1] = mfma16(pa, cat8(t2, t3), oacc[1]);
      oacc[2] = mfma16(pa, cat8(t4, t5), oacc[2]);
      oacc[3] = mfma16(pa, cat8(t6, t7), oacc[3]);
    }
    __syncthreads();
  }

  float lr[4];
#pragma unroll
  for (int r = 0; r < 4; r++) lr[r] = __shfl(lrow, (lane & 48) | (hi * 4 + r));
#pragma unroll
  for (int n = 0; n < 4; n++)
#pragma unroll
    for (int r = 0; r < 4; r++) {
      const int q = qbase + hi * 4 + r;
      const int dk = n * 16 + frow;
      outb[(size_t)(b * Ss + q) * 1024 + h * 64 + dk] = f2bf(oacc[n][r] / lr[r]);
    }
}

// ---------------- fused residual + bias + LayerNorm ----------------
__global__ __launch_bounds__(256) void ln_fuse(const float* __restrict__ a,
                                               const float* __restrict__ c,
                                               const float* __restrict__ bias,
                                               const float* __restrict__ g,
                                               const float* __restrict__ be,
                                               float* __restrict__ of,
                                               u16* __restrict__ ob) {
  __shared__ float red[4];
  const int tid = threadIdx.x;
  const size_t base = (size_t)blockIdx.x * 1024 + tid * 4;
  float4 va = *(const float4*)(a + base);
  float4 vc = *(const float4*)(c + base);
  float4 vb = *(const float4*)(bias + tid * 4);
  const float s0 = va.x + vc.x + vb.x, s1 = va.y + vc.y + vb.y;
  const float s2 = va.z + vc.z + vb.z, s3 = va.w + vc.w + vb.w;
  float sum = s0 + s1 + s2 + s3;
#pragma unroll
  for (int o = 32; o; o >>= 1) sum += __shfl_xor(sum, o);
  if ((tid & 63) == 0) red[tid >> 6] = sum;
  __syncthreads();
  const float mu = (red[0] + red[1] + red[2] + red[3]) * (1.f / 1024.f);
  __syncthreads();
  const float d0 = s0 - mu, d1 = s1 - mu, d2 = s2 - mu, d3 = s3 - mu;
  float vs = d0 * d0 + d1 * d1 + d2 * d2 + d3 * d3;
#pragma unroll
  for (int o = 32; o; o >>= 1) vs += __shfl_xor(vs, o);
  if ((tid & 63) == 0) red[tid >> 6] = vs;
  __syncthreads();
  const float var = (red[0] + red[1] + red[2] + red[3]) * (1.f / 1024.f);
  const float rs = rsqrtf(var + 1e-5f);
  float4 vg = *(const float4*)(g + tid * 4);
  float4 ve = *(const float4*)(be + tid * 4);
  const float y0 = d0 * rs * vg.x + ve.x, y1 = d1 * rs * vg.y + ve.y;
  const float y2 = d2 * rs * vg.z + ve.z, y3 = d3 * rs * vg.w + ve.w;
  if (of) { float4 y; y.x = y0; y.y = y1; y.z = y2; y.w = y3; *(float4*)(of + base) = y; }
  if (ob) { u16x4 o; o[0] = f2bf(y0); o[1] = f2bf(y1); o[2] = f2bf(y2); o[3] = f2bf(y3);
            *(u16x4*)(ob + base) = o; }
}

extern "C" void kernel_launch(void* const* d_in, const int* in_sizes, int n_in,
                              void* d_out, int out_size, void* d_ws, size_t ws_size,
                              hipStream_t stream) {
  const float* src = (const float*)d_in[0];
  const int* mask = (const int*)d_in[1];
  const float* Wq = (const float*)d_in[2];
  const float* Wk = (const float*)d_in[3];
  const float* Wv = (const float*)d_in[4];
  const float* Wo = (const float*)d_in[5];
  const float* bo = (const float*)d_in[6];
  const float* g1 = (const float*)d_in[7];
  const float* be1 = (const float*)d_in[8];
  const float* W1 = (const float*)d_in[9];
  const float* b1 = (const float*)d_in[10];
  const float* W2 = (const float*)d_in[11];
  const float* b2 = (const float*)d_in[12];
  const float* g2 = (const float*)d_in[13];
  const float* be2 = (const float*)d_in[14];
  float* outp = (float*)d_out;
  (void)in_sizes; (void)n_in; (void)out_size; (void)ws_size;

  char* ws = (char*)d_ws;
  size_t off = 0;
  auto take = [&](size_t bytes) -> char* {
    char* p = ws + off;
    off = (off + bytes + 255) & ~(size_t)255;
    return p;
  };
  u16* srcb  = (u16*)take((size_t)BS * Dd * 2);
  u16* wqkvt = (u16*)take((size_t)3 * Dd * Dd * 2);
  u16* wot   = (u16*)take((size_t)Dd * Dd * 2);
  u16* w1t   = (u16*)take((size_t)Dd * DFF * 2);
  u16* w2t   = (u16*)take((size_t)DFF * Dd * 2);
  char* qkvr = take((size_t)BS * 3 * Dd * 2);
  u16* qkvb  = (u16*)qkvr;
  float* Cf  = (float*)qkvr;
  u16* attnb = (u16*)take((size_t)BS * Dd * 2);
  float* xf  = (float*)take((size_t)BS * Dd * 4);
  u16* hb    = (u16*)take((size_t)BS * DFF * 2);
  int* flags = (int*)take(256);

  cast_src_k<<<2048, 256, 0, stream>>>(src, srcb, BS * Dd);
  transpose_cast<<<dim3(32, 32), 256, 0, stream>>>(Wq, wqkvt,                Dd, Dd);
  transpose_cast<<<dim3(32, 32), 256, 0, stream>>>(Wk, wqkvt + Dd * Dd,      Dd, Dd);
  transpose_cast<<<dim3(32, 32), 256, 0, stream>>>(Wv, wqkvt + 2 * Dd * Dd,  Dd, Dd);
  transpose_cast<<<dim3(32, 32), 256, 0, stream>>>(Wo, wot, Dd, Dd);
  transpose_cast<<<dim3(128, 32), 256, 0, stream>>>(W1, w1t, Dd, DFF);
  transpose_cast<<<dim3(32, 128), 256, 0, stream>>>(W2, w2t, DFF, Dd);
  mask_init_k<<<1, 64, 0, stream>>>(flags);
  mask_check_k<<<2048, 256, 0, stream>>>(mask, flags, Bb * Ss * Ss);

  // QKV projection: 128x256 8-phase, 768 blocks = 3.0 rounds (Q pre-scaled QSCALE)
  gemm8ph<3><<<dim3(3 * Dd / 256, BS / 128), 512, 0, stream>>>(srcb, wqkvt, nullptr, qkvb,
                                                               BS, 3 * Dd, Dd);
  attn_fwd<<<Bb * Hh * (Ss / 64), 256, 0, stream>>>(qkvb, mask, flags, attnb);
  // Wo: 128x256 8-phase, 256 blocks = 1.0 round
  gemm8ph<0><<<dim3(Dd / 256, BS / 128), 512, 0, stream>>>(attnb, wot, nullptr, Cf,
                                                           BS, Dd, Dd);
  ln_fuse<<<BS, 256, 0, stream>>>(src, Cf, bo, g1, be1, xf, attnb);
  // W1: 256^2 8-phase, 512 blocks = 2.0 rounds
  gemm8p<2><<<dim3(DFF / 256, BS / 256), 512, 0, stream>>>(attnb, w1t, b1, hb,
                                                           BS, DFF, Dd);
  // W2: 128x256 8-phase, 256 blocks = 1.0 round (K=4096)
  gemm8ph<0><<<dim3(Dd / 256, BS / 128), 512, 0, stream>>>(hb, w2t, nullptr, Cf,
                                                           BS, Dd, DFF);
  ln_fuse<<<BS, 256, 0, stream>>>(xf, Cf, b2, g2, be2, outp, nullptr);
}

// Round 5
// 636.920 us; speedup vs baseline: 1.0532x; 1.0532x over previous
//
#include <hip/hip_runtime.h>

#define DEV static __device__ __forceinline__

typedef unsigned short u16;
typedef __attribute__((ext_vector_type(8))) short bf16x8;     // 8 bf16 in 4 VGPRs
typedef __attribute__((ext_vector_type(8))) unsigned short u16x8;
typedef __attribute__((ext_vector_type(4))) unsigned short u16x4;
typedef __attribute__((ext_vector_type(4))) float f32x4;

static constexpr int Bb = 4, Ss = 2048, Dd = 1024, Hh = 16, DFF = 4096;
static constexpr int BS = Bb * Ss;  // 8192 rows
// 1/sqrt(64) * log2(e): QK^T then exp2 == exp(S/8)
#define QSCALE 0.18033688011112042f

DEV u16 f2bf(float f) {
  union { float f; unsigned u; } x; x.f = f;
  unsigned r = x.u + 0x7fffu + ((x.u >> 16) & 1u);  // RNE
  return (u16)(r >> 16);
}

DEV unsigned cvtpk(float lo, float hi) {  // 2xf32 -> packed 2xbf16 (lo->[15:0])
  unsigned r;
  asm("v_cvt_pk_bf16_f32 %0, %1, %2" : "=v"(r) : "v"(lo), "v"(hi));
  return r;
}

DEV void gload_lds16(const void* g, void* l) {
  __builtin_amdgcn_global_load_lds(
      (const __attribute__((address_space(1))) unsigned int*)g,
      (__attribute__((address_space(3))) unsigned int*)l, 16, 0, 0);
}

DEV unsigned lds_addr(const void* p) {
  return (unsigned)(size_t)(const __attribute__((address_space(3))) void*)p;
}

DEV f32x4 mfma16(bf16x8 a, bf16x8 b, f32x4 c) {
  return __builtin_amdgcn_mfma_f32_16x16x32_bf16(a, b, c, 0, 0, 0);
}

DEV bf16x8 cat8(u16x4 a, u16x4 b) {
  bf16x8 v;
#pragma unroll
  for (int j = 0; j < 4; j++) { v[j] = (short)a[j]; v[j + 4] = (short)b[j]; }
  return v;
}

// XCD-aware bijective remap (T1): hardware round-robins linear id over 8 XCDs;
// give XCD x the blocks of whole (TX x TY) grid-tiles so operand panels L2-fit.
// requires (gx/TX)*(gy/TY) % 8 == 0.
template <int TX, int TY, int NTX>
DEV void xcd_tile_remap(int id, int& bx, int& by) {
  const int jj = id >> 3, xx = id & 7;
  const int tt = jj / (TX * TY);
  const int pp = jj - tt * (TX * TY);
  const int gg = tt * 8 + xx;
  const int tgx = gg % NTX, tgy = gg / NTX;
  bx = tgx * TX + pp % TX;
  by = tgy * TY + pp / TX;
}

#define TRRD(dst, addr, OFF)                                     \
  asm volatile("ds_read_b64_tr_b16 %0, %1 offset:" #OFF         \
               : "=v"(dst) : "v"(addr))

// ---------------- elementwise cast fp32 -> bf16 ----------------
__global__ void cast_src_k(const float* __restrict__ in, u16* __restrict__ outp, int n) {
  int i = (blockIdx.x * 256 + threadIdx.x) * 4;
  const int stride = gridDim.x * 256 * 4;
  for (; i < n; i += stride) {
    float4 v = *(const float4*)(in + i);
    u16x4 o; o[0] = f2bf(v.x); o[1] = f2bf(v.y); o[2] = f2bf(v.z); o[3] = f2bf(v.w);
    *(u16x4*)(outp + i) = o;
  }
}

// ---------------- transpose + cast: W (KxN f32) -> Wt (NxK bf16) ----------------
__global__ __launch_bounds__(256) void transpose_cast(const float* __restrict__ W,
                                                      u16* __restrict__ Wt, int K, int N) {
  __shared__ float t[32][33];
  const int n0 = blockIdx.x * 32, k0 = blockIdx.y * 32;
  const int tx = threadIdx.x & 31, ty = threadIdx.x >> 5;
#pragma unroll
  for (int i = 0; i < 4; i++) t[ty + i * 8][tx] = W[(size_t)(k0 + ty + i * 8) * N + n0 + tx];
  __syncthreads();
#pragma unroll
  for (int i = 0; i < 4; i++) Wt[(size_t)(n0 + ty + i * 8) * K + k0 + tx] = f2bf(t[tx][ty + i * 8]);
}

// ---------------- mask summary ----------------
__global__ void mask_init_k(int* flags) { if (threadIdx.x < 4) flags[threadIdx.x] = 1; }
__global__ void mask_check_k(const int* __restrict__ mask, int* __restrict__ flags, int n) {
  int i = blockIdx.x * 256 + threadIdx.x;
  const int st = gridDim.x * 256;
  for (; i < n; i += st) if (mask[i] == 0) flags[i >> 22] = 0;  // S*S = 2^22
}

// ---------------- 256^2 8-phase GEMM (T2+T3+T4+T5, + T1 swizzle) ----------------
template <int MODE, int TX, int TY, int NTX>
__global__ __launch_bounds__(512, 2) void gemm8p(const u16* __restrict__ A,
                                                 const u16* __restrict__ Bt,
                                                 const float* __restrict__ bias,
                                                 void* __restrict__ C,
                                                 int M, int N, int K) {
  __shared__ alignas(128) u16 lds[65536];
  const int tid = threadIdx.x, lane = tid & 63, w = tid >> 6;
  const int wm = w >> 2, wc = w & 3;
  const int frow = lane & 15, hi = lane >> 4;
  int bxs, bys;
  xcd_tile_remap<TX, TY, NTX>(blockIdx.y * gridDim.x + blockIdx.x, bxs, bys);
  const int bm = bys * 256, bn = bxs * 256;
  const int NT = K >> 6;

  const int cs = ((tid & 7) ^ ((tid >> 3) & 7)) * 8;
  const int sr = w * 8 + ((lane >> 3) & 7);
  const u16* Ab = A + (size_t)(bm + sr) * K + cs;
  const u16* Bbp = Bt + (size_t)(bn + sr) * K + cs;
  u16* lw = lds + w * 512;

  const int c0 = (hi * 8) ^ ((frow & 7) << 3);
  const u16* Abase = lds + wm * 8192 + frow * 64;
  const u16* Bbase = lds + 32768 + (wc >> 1) * 8192 + (wc & 1) * 4096 + frow * 64;

  f32x4 acc[8][4] = {};
  bf16x8 af0[4][2], af1[4][2], bf0[2][2], bf1[2][2];

#define STG(Pb, hh, kk, reg)                                                     \
  do {                                                                           \
    gload_lds16((Pb) + (size_t)((hh) * 128) * K + (kk), lw + (reg));             \
    gload_lds16((Pb) + (size_t)((hh) * 128 + 64) * K + (kk), lw + (reg) + 4096); \
  } while (0)
#define LDA(dst, sb, mh)                                                              \
  do {                                                                                \
    _Pragma("unroll") for (int m = 0; m < 4; m++) {                                   \
      dst[m][0] = *(const bf16x8*)(Abase + (sb) + ((mh) * 4 + m) * 1024 + c0);        \
      dst[m][1] = *(const bf16x8*)(Abase + (sb) + ((mh) * 4 + m) * 1024 + (c0 ^ 32)); \
    }                                                                                 \
  } while (0)
#define LDB(dst, sb, nh)                                                              \
  do {                                                                                \
    _Pragma("unroll") for (int n = 0; n < 2; n++) {                                   \
      dst[n][0] = *(const bf16x8*)(Bbase + (sb) + ((nh) * 2 + n) * 1024 + c0);        \
      dst[n][1] = *(const bf16x8*)(Bbase + (sb) + ((nh) * 2 + n) * 1024 + (c0 ^ 32)); \
    }                                                                                 \
  } while (0)
#define MM(AF, BF, mh, nh)                                                             \
  do {                                                                                 \
    __builtin_amdgcn_s_setprio(1);                                                     \
    _Pragma("unroll") for (int m = 0; m < 4; m++) _Pragma("unroll") for (int n = 0;    \
                                                                        n < 2; n++) { \
      acc[(mh)*4+m][(nh)*2+n] = mfma16(AF[m][0], BF[n][0], acc[(mh)*4+m][(nh)*2+n]);   \
      acc[(mh)*4+m][(nh)*2+n] = mfma16(AF[m][1], BF[n][1], acc[(mh)*4+m][(nh)*2+n]);   \
    }                                                                                  \
    __builtin_amdgcn_s_setprio(0);                                                     \
  } while (0)
#define BAR asm volatile("s_barrier" ::: "memory")
#define VMC(n) asm volatile("s_waitcnt vmcnt(" #n ")" ::: "memory")

  STG(Ab, 0, 0, 0);        STG(Ab, 1, 0, 8192);
  STG(Bbp, 0, 0, 32768);   STG(Bbp, 1, 0, 40960);
  STG(Ab, 0, 64, 16384);   STG(Ab, 1, 64, 24576);
  VMC(0);
  BAR;

  const int NI = NT >> 1;
#pragma unroll 1
  for (int i = 0; i < NI; ++i) {
    const int T = i * 2;
    const int kT1 = (T + 1) << 6;
    const int kT2 = (T + 2 < NT ? T + 2 : NT - 1) << 6;
    const int kT3 = (T + 3 < NT ? T + 3 : NT - 1) << 6;
    LDA(af0, 0, 0); LDB(bf0, 0, 0);
    STG(Bbp, 0, kT1, 49152);
    BAR; MM(af0, bf0, 0, 0); BAR;
    LDA(af1, 0, 1);
    STG(Bbp, 1, kT1, 57344);
    BAR; MM(af1, bf0, 1, 0); BAR;
    LDB(bf1, 0, 1);
    STG(Ab, 0, kT2, 0);
    BAR; MM(af0, bf1, 0, 1); BAR;
    STG(Ab, 1, kT2, 8192);
    VMC(4); BAR; MM(af1, bf1, 1, 1); BAR;
    LDA(af0, 16384, 0); LDB(bf0, 16384, 0);
    STG(Bbp, 0, kT2, 32768);
    BAR; MM(af0, bf0, 0, 0); BAR;
    LDA(af1, 16384, 1);
    STG(Bbp, 1, kT2, 40960);
    BAR; MM(af1, bf0, 1, 0); BAR;
    LDB(bf1, 16384, 1);
    STG(Ab, 0, kT3, 16384);
    BAR; MM(af0, bf1, 0, 1); BAR;
    STG(Ab, 1, kT3, 24576);
    VMC(4); BAR; MM(af1, bf1, 1, 1); BAR;
  }

#undef STG
#undef LDA
#undef LDB
#undef MM
#undef BAR
#undef VMC

#pragma unroll
  for (int m = 0; m < 8; m++) {
#pragma unroll
    for (int n = 0; n < 4; n++) {
      const int col = bn + wc * 64 + n * 16 + frow;
      const float bv = (MODE == 2) ? bias[col] : 0.f;
      const float sc = (MODE == 3 && col < Dd) ? QSCALE : 1.f;
#pragma unroll
      for (int r = 0; r < 4; r++) {
        const int row = bm + wm * 128 + m * 16 + hi * 4 + r;
        float v = acc[m][n][r];
        if (MODE == 2) v = fmaxf(v + bv, 0.f);
        if (MODE == 3) v *= sc;
        if (MODE == 0) ((float*)C)[(size_t)row * N + col] = v;
        else           ((u16*)C)[(size_t)row * N + col] = f2bf(v);
      }
    }
  }
}

// ---------------- 128x256 8-phase GEMM (+ T1 swizzle) ----------
template <int MODE, int TX, int TY, int NTX>
__global__ __launch_bounds__(512, 2) void gemm8ph(const u16* __restrict__ A,
                                                  const u16* __restrict__ Bt,
                                                  const float* __restrict__ bias,
                                                  void* __restrict__ C,
                                                  int M, int N, int K) {
  __shared__ alignas(128) u16 lds[49152];
  const int tid = threadIdx.x, lane = tid & 63, w = tid >> 6;
  const int wm = w >> 2, wc = w & 3;
  const int frow = lane & 15, hi = lane >> 4;
  int bxs, bys;
  xcd_tile_remap<TX, TY, NTX>(blockIdx.y * gridDim.x + blockIdx.x, bxs, bys);
  const int bm = bys * 128, bn = bxs * 256;
  const int NT = K >> 6;

  const int cs = ((tid & 7) ^ ((tid >> 3) & 7)) * 8;
  const int sr = w * 8 + ((lane >> 3) & 7);
  const u16* Ab = A + (size_t)(bm + sr) * K + cs;
  const u16* Bbp = Bt + (size_t)(bn + sr) * K + cs;
  u16* lwA = lds + w * 512;
  u16* lwB = lds + 16384 + w * 512;

  const int c0 = (hi * 8) ^ ((frow & 7) << 3);
  const u16* Abase = lds + wm * 4096 + frow * 64;
  const u16* Bbase = lds + 16384 + wc * 4096 + frow * 64;

  f32x4 acc[4][4] = {};
  bf16x8 af0[2][2], af1[2][2], bf0[2][2], bf1[2][2];

#define STGA(kk, reg)                                              \
  do {                                                             \
    gload_lds16(Ab + (kk), lwA + (reg));                           \
    gload_lds16(Ab + (size_t)64 * K + (kk), lwA + (reg) + 4096);   \
  } while (0)
#define STGB(hh, kk, reg)                                                            \
  do {                                                                               \
    gload_lds16(Bbp + (size_t)((hh) * 128) * K + (kk), lwB + (reg) + (hh) * 8192);   \
    gload_lds16(Bbp + (size_t)((hh) * 128 + 64) * K + (kk),                          \
                lwB + (reg) + (hh) * 8192 + 4096);                                   \
  } while (0)
#define LDA2(dst, sb, mh)                                                             \
  do {                                                                                \
    _Pragma("unroll") for (int m = 0; m < 2; m++) {                                   \
      dst[m][0] = *(const bf16x8*)(Abase + (sb) + ((mh) * 2 + m) * 1024 + c0);        \
      dst[m][1] = *(const bf16x8*)(Abase + (sb) + ((mh) * 2 + m) * 1024 + (c0 ^ 32)); \
    }                                                                                 \
  } while (0)
#define LDB2(dst, sb, nh)                                                             \
  do {                                                                                \
    _Pragma("unroll") for (int n = 0; n < 2; n++) {                                   \
      dst[n][0] = *(const bf16x8*)(Bbase + (sb) + ((nh) * 2 + n) * 1024 + c0);        \
      dst[n][1] = *(const bf16x8*)(Bbase + (sb) + ((nh) * 2 + n) * 1024 + (c0 ^ 32)); \
    }                                                                                 \
  } while (0)
#define MM2(AF, BF, mh, nh)                                                            \
  do {                                                                                 \
    __builtin_amdgcn_s_setprio(1);                                                     \
    _Pragma("unroll") for (int m = 0; m < 2; m++) _Pragma("unroll") for (int n = 0;    \
                                                                        n < 2; n++) { \
      acc[(mh)*2+m][(nh)*2+n] = mfma16(AF[m][0], BF[n][0], acc[(mh)*2+m][(nh)*2+n]);   \
      acc[(mh)*2+m][(nh)*2+n] = mfma16(AF[m][1], BF[n][1], acc[(mh)*2+m][(nh)*2+n]);   \
    }                                                                                  \
    __builtin_amdgcn_s_setprio(0);                                                     \
  } while (0)
#define BAR asm volatile("s_barrier" ::: "memory")
#define VMC(n) asm volatile("s_waitcnt vmcnt(" #n ")" ::: "memory")

  STGA(0, 0);
  STGB(0, 0, 0); STGB(1, 0, 0);
  STGA(64, 8192);
  VMC(0);
  BAR;

  const int NI = NT >> 1;
#pragma unroll 1
  for (int i = 0; i < NI; ++i) {
    const int T = i * 2;
    const int kT1 = (T + 1) << 6;
    const int kT2 = (T + 2 < NT ? T + 2 : NT - 1) << 6;
    const int kT3 = (T + 3 < NT ? T + 3 : NT - 1) << 6;
    LDA2(af0, 0, 0); LDB2(bf0, 0, 0);
    STGB(0, kT1, 16384);
    BAR; MM2(af0, bf0, 0, 0); BAR;
    LDA2(af1, 0, 1);
    STGB(1, kT1, 16384);
    BAR; MM2(af1, bf0, 1, 0); BAR;
    LDB2(bf1, 0, 1);
    STGA(kT2, 0);
    BAR; MM2(af0, bf1, 0, 1); BAR;
    VMC(2); BAR; MM2(af1, bf1, 1, 1); BAR;
    LDA2(af0, 8192, 0); LDB2(bf0, 16384, 0);
    STGB(0, kT2, 0);
    BAR; MM2(af0, bf0, 0, 0); BAR;
    LDA2(af1, 8192, 1);
    STGB(1, kT2, 0);
    BAR; MM2(af1, bf0, 1, 0); BAR;
    LDB2(bf1, 16384, 1);
    STGA(kT3, 8192);
    BAR; MM2(af0, bf1, 0, 1); BAR;
    VMC(2); BAR; MM2(af1, bf1, 1, 1); BAR;
  }

#undef STGA
#undef STGB
#undef LDA2
#undef LDB2
#undef MM2
#undef BAR
#undef VMC

#pragma unroll
  for (int m = 0; m < 4; m++) {
#pragma unroll
    for (int n = 0; n < 4; n++) {
      const int col = bn + wc * 64 + n * 16 + frow;
      const float bv = (MODE == 2) ? bias[col] : 0.f;
      const float sc = (MODE == 3 && col < Dd) ? QSCALE : 1.f;
#pragma unroll
      for (int r = 0; r < 4; r++) {
        const int row = bm + wm * 64 + m * 16 + hi * 4 + r;
        float v = acc[m][n][r];
        if (MODE == 2) v = fmaxf(v + bv, 0.f);
        if (MODE == 3) v *= sc;
        if (MODE == 0) ((float*)C)[(size_t)row * N + col] = v;
        else           ((u16*)C)[(size_t)row * N + col] = f2bf(v);
      }
    }
  }
}

// ---------------- fused flash attention (R4 + T1 XCD swizzle) ----------------
__global__ __launch_bounds__(256, 3) void attn_fwd(const u16* __restrict__ qkv,
                                                   const int* __restrict__ mask,
                                                   const int* __restrict__ mflag,
                                                   u16* __restrict__ outb) {
  __shared__ alignas(128) u16 Ks[2 * 4096];
  __shared__ alignas(128) u16 Vs[2 * 4096];
  __shared__ alignas(16)  u16 Pl[4 * 16 * 72];

  // T1: chunk 2048 blocks into 8 XCD groups of 256 -> each XCD sees 8 (b,h)
  // pairs; their K/V (8 x 0.5 MB) fit the 4 MiB per-XCD L2.
  const int id = blockIdx.x;
  const int bx = (id & 7) * 256 + (id >> 3);
  const int qt = bx & 31;
  const int h = (bx >> 5) & 15;
  const int b = bx >> 9;
  const int tid = threadIdx.x;
  const int lane = tid & 63;
  const int w = tid >> 6;
  const int frow = lane & 15, hi = lane >> 4;
  const int qbase = qt * 64 + w * 16;

  bf16x8 qf[2];
  {
    const u16* qp = qkv + (size_t)(b * Ss + qbase + frow) * 3072 + h * 64 + hi * 8;
    qf[0] = *(const bf16x8*)(qp);
    qf[1] = *(const bf16x8*)(qp + 32);
  }
  const int allones = mflag[b];
  u16* Plw = Pl + w * (16 * 72);

  f32x4 oacc[4] = {};
  float mrow = -1e30f, lrow = 0.f;

  const size_t kvb = (size_t)(b * Ss) * 3072 + 1024 + h * 64;
  const int kcol_s = tid >> 2;
  const int dsw = ((tid & 3) ^ (kcol_s & 3)) * 8;
  const u16* Kg0 = qkv + kvb + (size_t)kcol_s * 3072 + dsw;
  const u16* Kg1 = Kg0 + 32;
  int kV0, dkV0, kV1, dkV1;
  {
    int p = tid, T = p >> 3, j = (p >> 1) & 3, hh = p & 1;
    kV0 = ((T >> 3) & 1) * 32 + (T & 3) * 8 + ((T >> 2) & 1) * 4 + j;
    dkV0 = ((T >> 4) & 3) * 16 + hh * 8;
    p = tid + 256; T = p >> 3; j = (p >> 1) & 3; hh = p & 1;
    kV1 = ((T >> 3) & 1) * 32 + (T & 3) * 8 + ((T >> 2) & 1) * 4 + j;
    dkV1 = ((T >> 4) & 3) * 16 + hh * 8;
  }
  const u16* Vg0 = qkv + kvb + 1024 + (size_t)kV0 * 3072 + dkV0;
  const u16* Vg1 = qkv + kvb + 1024 + (size_t)kV1 * 3072 + dkV1;

  const unsigned vbase = lds_addr(Vs) + lane * 8;

  gload_lds16(Kg0, Ks + w * 512);
  gload_lds16(Kg1, Ks + 2048 + w * 512);
  gload_lds16(Vg0, Vs + w * 512);
  gload_lds16(Vg1, Vs + 2048 + w * 512);
  __syncthreads();

#pragma unroll 1
  for (int kt = 0; kt < 32; kt++) {
    const int cur = kt & 1;
    if (kt < 31) {
      const size_t soff = (size_t)(kt + 1) * 64 * 3072;
      u16* Kb = Ks + (cur ^ 1) * 4096;
      u16* Vb = Vs + (cur ^ 1) * 4096;
      gload_lds16(Kg0 + soff, Kb + w * 512);
      gload_lds16(Kg1 + soff, Kb + 2048 + w * 512);
      gload_lds16(Vg0 + soff, Vb + w * 512);
      gload_lds16(Vg1 + soff, Vb + 2048 + w * 512);
    }
    const u16* Kbuf = Ks + cur * 4096;

    f32x4 sacc[4] = {};
    const int kswz = (hi ^ (frow & 3)) * 8;
#pragma unroll
    for (int ks = 0; ks < 2; ks++)
#pragma unroll
      for (int n = 0; n < 4; n++) {
        bf16x8 kf = *(const bf16x8*)&Kbuf[ks * 2048 + (n * 16 + frow) * 32 + kswz];
        sacc[n] = mfma16(kf, qf[ks], sacc[n]);
      }

    const int srow = kt * 64;
    float sv[16];
#pragma unroll
    for (int n = 0; n < 4; n++)
#pragma unroll
      for (int r = 0; r < 4; r++) {
        float s = sacc[n][r];  // already in log2 units (QSCALE folded)
        if (!allones) {
          const int qq = b * Ss + qbase + frow;
          const int kk = srow + n * 16 + hi * 4 + r;
          if (mask[(size_t)qq * Ss + kk] == 0) s = -1e30f;
        }
        sv[n * 4 + r] = s;
      }
    float mt = sv[0];
#pragma unroll
    for (int i = 1; i < 16; i++) mt = fmaxf(mt, sv[i]);
    mt = fmaxf(mt, __shfl_xor(mt, 16));
    mt = fmaxf(mt, __shfl_xor(mt, 32));
    if (__any(mt > mrow + 8.f)) {
      const float mn = fmaxf(mrow, mt);
      const float al = exp2f(mrow - mn);
      mrow = mn;
      lrow *= al;
      float alr[4];
#pragma unroll
      for (int r = 0; r < 4; r++) alr[r] = __shfl(al, (lane & 48) | (hi * 4 + r));
#pragma unroll
      for (int n = 0; n < 4; n++) {
        oacc[n][0] *= alr[0]; oacc[n][1] *= alr[1];
        oacc[n][2] *= alr[2]; oacc[n][3] *= alr[3];
      }
    }
    float ps[16], rs = 0.f;
#pragma unroll
    for (int i = 0; i < 16; i++) { ps[i] = exp2f(sv[i] - mrow); rs += ps[i]; }
    rs += __shfl_xor(rs, 16);
    rs += __shfl_xor(rs, 32);
    lrow += rs;
#pragma unroll
    for (int n = 0; n < 4; n++) {
      *(unsigned*)(Plw + frow * 72 + n * 16 + hi * 4)     = cvtpk(ps[n * 4 + 0], ps[n * 4 + 1]);
      *(unsigned*)(Plw + frow * 72 + n * 16 + hi * 4 + 2) = cvtpk(ps[n * 4 + 2], ps[n * 4 + 3]);
    }

    const unsigned vaddr = vbase + (cur << 13);
    u16x4 t0, t1, t2, t3, t4, t5, t6, t7;
    TRRD(t0, vaddr, 0);    TRRD(t1, vaddr, 512);
    TRRD(t2, vaddr, 2048); TRRD(t3, vaddr, 2560);
    TRRD(t4, vaddr, 4096); TRRD(t5, vaddr, 4608);
    TRRD(t6, vaddr, 6144); TRRD(t7, vaddr, 6656);
    {
      bf16x8 pa = *(const bf16x8*)&Plw[frow * 72 + hi * 8];
      asm volatile("s_waitcnt lgkmcnt(0)" ::: "memory");
      __builtin_amdgcn_sched_barrier(0);
      oacc[0] = mfma16(pa, cat8(t0, t1), oacc[0]);
      oacc[1] = mfma16(pa, cat8(t2, t3), oacc[1]);
      oacc[2] = mfma16(pa, cat8(t4, t5), oacc[2]);
      oacc[3] = mfma16(pa, cat8(t6, t7), oacc[3]);
    }
    TRRD(t0, vaddr, 1024); TRRD(t1, vaddr, 1536);
    TRRD(t2, vaddr, 3072); TRRD(t3, vaddr, 3584);
    TRRD(t4, vaddr, 5120); TRRD(t5, vaddr, 5632);
    TRRD(t6, vaddr, 7168); TRRD(t7, vaddr, 7680);
    {
      bf16x8 pa = *(const bf16x8*)&Plw[frow * 72 + 32 + hi * 8];
      asm volatile("s_waitcnt lgkmcnt(0)" ::: "memory");
      __builtin_amdgcn_sched_barrier(0);
      oacc[0] = mfma16(pa, cat8(t0, t1), oacc[0]);
      oacc[1] = mfma16(pa, cat8(t2, t3), oacc[1]);
      oacc[2] = mfma16(pa, cat8(t4, t5), oacc[2]);
      oacc[3] = mfma16(pa, cat8(t6, t7), oacc[3]);
    }
    __syncthreads();
  }

  float lr[4];
#pragma unroll
  for (int r = 0; r < 4; r++) lr[r] = __shfl(lrow, (lane & 48) | (hi * 4 + r));
#pragma unroll
  for (int n = 0; n < 4; n++)
#pragma unroll
    for (int r = 0; r < 4; r++) {
      const int q = qbase + hi * 4 + r;
      const int dk = n * 16 + frow;
      outb[(size_t)(b * Ss + q) * 1024 + h * 64 + dk] = f2bf(oacc[n][r] / lr[r]);
    }
}

// ---------------- fused residual + bias + LayerNorm ----------------
__global__ __launch_bounds__(256) void ln_fuse(const float* __restrict__ a,
                                               const float* __restrict__ c,
                                               const float* __restrict__ bias,
                                               const float* __restrict__ g,
                                               const float* __restrict__ be,
                                               float* __restrict__ of,
                                               u16* __restrict__ ob) {
  __shared__ float red[4];
  const int tid = threadIdx.x;
  const size_t base = (size_t)blockIdx.x * 1024 + tid * 4;
  float4 va = *(const float4*)(a + base);
  float4 vc = *(const float4*)(c + base);
  float4 vb = *(const float4*)(bias + tid * 4);
  const float s0 = va.x + vc.x + vb.x, s1 = va.y + vc.y + vb.y;
  const float s2 = va.z + vc.z + vb.z, s3 = va.w + vc.w + vb.w;
  float sum = s0 + s1 + s2 + s3;
#pragma unroll
  for (int o = 32; o; o >>= 1) sum += __shfl_xor(sum, o);
  if ((tid & 63) == 0) red[tid >> 6] = sum;
  __syncthreads();
  const float mu = (red[0] + red[1] + red[2] + red[3]) * (1.f / 1024.f);
  __syncthreads();
  const float d0 = s0 - mu, d1 = s1 - mu, d2 = s2 - mu, d3 = s3 - mu;
  float vs = d0 * d0 + d1 * d1 + d2 * d2 + d3 * d3;
#pragma unroll
  for (int o = 32; o; o >>= 1) vs += __shfl_xor(vs, o);
  if ((tid & 63) == 0) red[tid >> 6] = vs;
  __syncthreads();
  const float var = (red[0] + red[1] + red[2] + red[3]) * (1.f / 1024.f);
  const float rs = rsqrtf(var + 1e-5f);
  float4 vg = *(const float4*)(g + tid * 4);
  float4 ve = *(const float4*)(be + tid * 4);
  const float y0 = d0 * rs * vg.x + ve.x, y1 = d1 * rs * vg.y + ve.y;
  const float y2 = d2 * rs * vg.z + ve.z, y3 = d3 * rs * vg.w + ve.w;
  if (of) { float4 y; y.x = y0; y.y = y1; y.z = y2; y.w = y3; *(float4*)(of + base) = y; }
  if (ob) { u16x4 o; o[0] = f2bf(y0); o[1] = f2bf(y1); o[2] = f2bf(y2); o[3] = f2bf(y3);
            *(u16x4*)(ob + base) = o; }
}

extern "C" void kernel_launch(void* const* d_in, const int* in_sizes, int n_in,
                              void* d_out, int out_size, void* d_ws, size_t ws_size,
                              hipStream_t stream) {
  const float* src = (const float*)d_in[0];
  const int* mask = (const int*)d_in[1];
  const float* Wq = (const float*)d_in[2];
  const float* Wk = (const float*)d_in[3];
  const float* Wv = (const float*)d_in[4];
  const float* Wo = (const float*)d_in[5];
  const float* bo = (const float*)d_in[6];
  const float* g1 = (const float*)d_in[7];
  const float* be1 = (const float*)d_in[8];
  const float* W1 = (const float*)d_in[9];
  const float* b1 = (const float*)d_in[10];
  const float* W2 = (const float*)d_in[11];
  const float* b2 = (const float*)d_in[12];
  const float* g2 = (const float*)d_in[13];
  const float* be2 = (const float*)d_in[14];
  float* outp = (float*)d_out;
  (void)in_sizes; (void)n_in; (void)out_size; (void)ws_size;

  char* ws = (char*)d_ws;
  size_t off = 0;
  auto take = [&](size_t bytes) -> char* {
    char* p = ws + off;
    off = (off + bytes + 255) & ~(size_t)255;
    return p;
  };
  u16* srcb  = (u16*)take((size_t)BS * Dd * 2);
  u16* wqkvt = (u16*)take((size_t)3 * Dd * Dd * 2);
  u16* wot   = (u16*)take((size_t)Dd * Dd * 2);
  u16* w1t   = (u16*)take((size_t)Dd * DFF * 2);
  u16* w2t   = (u16*)take((size_t)DFF * Dd * 2);
  char* qkvr = take((size_t)BS * 3 * Dd * 2);
  u16* qkvb  = (u16*)qkvr;
  float* Cf  = (float*)qkvr;
  u16* attnb = (u16*)take((size_t)BS * Dd * 2);
  float* xf  = (float*)take((size_t)BS * Dd * 4);
  u16* hb    = (u16*)take((size_t)BS * DFF * 2);
  int* flags = (int*)take(256);

  cast_src_k<<<2048, 256, 0, stream>>>(src, srcb, BS * Dd);
  transpose_cast<<<dim3(32, 32), 256, 0, stream>>>(Wq, wqkvt,                Dd, Dd);
  transpose_cast<<<dim3(32, 32), 256, 0, stream>>>(Wk, wqkvt + Dd * Dd,      Dd, Dd);
  transpose_cast<<<dim3(32, 32), 256, 0, stream>>>(Wv, wqkvt + 2 * Dd * Dd,  Dd, Dd);
  transpose_cast<<<dim3(32, 32), 256, 0, stream>>>(Wo, wot, Dd, Dd);
  transpose_cast<<<dim3(128, 32), 256, 0, stream>>>(W1, w1t, Dd, DFF);
  transpose_cast<<<dim3(32, 128), 256, 0, stream>>>(W2, w2t, DFF, Dd);
  mask_init_k<<<1, 64, 0, stream>>>(flags);
  mask_check_k<<<2048, 256, 0, stream>>>(mask, flags, Bb * Ss * Ss);

  // QKV: grid (12,64), XCD tile 3x8 (ws: 3x0.5 + 8x0.25 = 3.5 MB < L2)
  gemm8ph<3, 3, 8, 4><<<dim3(3 * Dd / 256, BS / 128), 512, 0, stream>>>(
      srcb, wqkvt, nullptr, qkvb, BS, 3 * Dd, Dd);
  attn_fwd<<<Bb * Hh * (Ss / 64), 256, 0, stream>>>(qkvb, mask, flags, attnb);
  // Wo: grid (4,64), XCD tile 4x8 (ws: 4x0.5 + 8x0.25 = 4 MB)
  gemm8ph<0, 4, 8, 1><<<dim3(Dd / 256, BS / 128), 512, 0, stream>>>(
      attnb, wot, nullptr, Cf, BS, Dd, Dd);
  ln_fuse<<<BS, 256, 0, stream>>>(src, Cf, bo, g1, be1, xf, attnb);
  // W1: grid (16,32), XCD tile 4x4 (ws: 4x0.5 + 4x0.5 = 4 MB)
  gemm8p<2, 4, 4, 4><<<dim3(DFF / 256, BS / 256), 512, 0, stream>>>(
      attnb, w1t, b1, hb, BS, DFF, Dd);
  // W2: grid (4,64), XCD tile 2x2 (K=4096 streams; ws ~6 MB instantaneous less)
  gemm8ph<0, 2, 2, 2><<<dim3(Dd / 256, BS / 128), 512, 0, stream>>>(
      hb, w2t, nullptr, Cf, BS, Dd, DFF);
  ln_fuse<<<BS, 256, 0, stream>>>(xf, Cf, b2, g2, be2, outp, nullptr);
}

// Round 6
// 624.804 us; speedup vs baseline: 1.0736x; 1.0194x over previous
//
#include <hip/hip_runtime.h>

#define DEV static __device__ __forceinline__

typedef unsigned short u16;
typedef __attribute__((ext_vector_type(8))) short bf16x8;     // 8 bf16 in 4 VGPRs
typedef __attribute__((ext_vector_type(8))) unsigned short u16x8;
typedef __attribute__((ext_vector_type(4))) unsigned short u16x4;
typedef __attribute__((ext_vector_type(4))) float f32x4;

static constexpr int Bb = 4, Ss = 2048, Dd = 1024, Hh = 16, DFF = 4096;
static constexpr int BS = Bb * Ss;  // 8192 rows
// 1/sqrt(64) * log2(e): QK^T then exp2 == exp(S/8)
#define QSCALE 0.18033688011112042f

DEV u16 f2bf(float f) {
  union { float f; unsigned u; } x; x.f = f;
  unsigned r = x.u + 0x7fffu + ((x.u >> 16) & 1u);  // RNE
  return (u16)(r >> 16);
}

DEV unsigned cvtpk(float lo, float hi) {  // 2xf32 -> packed 2xbf16 (lo->[15:0])
  unsigned r;
  asm("v_cvt_pk_bf16_f32 %0, %1, %2" : "=v"(r) : "v"(lo), "v"(hi));
  return r;
}

DEV void gload_lds16(const void* g, void* l) {
  __builtin_amdgcn_global_load_lds(
      (const __attribute__((address_space(1))) unsigned int*)g,
      (__attribute__((address_space(3))) unsigned int*)l, 16, 0, 0);
}

DEV unsigned lds_addr(const void* p) {
  return (unsigned)(size_t)(const __attribute__((address_space(3))) void*)p;
}

DEV f32x4 mfma16(bf16x8 a, bf16x8 b, f32x4 c) {
  return __builtin_amdgcn_mfma_f32_16x16x32_bf16(a, b, c, 0, 0, 0);
}

DEV bf16x8 cat8(u16x4 a, u16x4 b) {
  bf16x8 v;
#pragma unroll
  for (int j = 0; j < 4; j++) { v[j] = (short)a[j]; v[j + 4] = (short)b[j]; }
  return v;
}

// XCD-aware bijective remap (T1)
template <int TX, int TY, int NTX>
DEV void xcd_tile_remap(int id, int& bx, int& by) {
  const int jj = id >> 3, xx = id & 7;
  const int tt = jj / (TX * TY);
  const int pp = jj - tt * (TX * TY);
  const int gg = tt * 8 + xx;
  const int tgx = gg % NTX, tgy = gg / NTX;
  bx = tgx * TX + pp % TX;
  by = tgy * TY + pp / TX;
}

#define TRRD(dst, addr, OFF)                                     \
  asm volatile("ds_read_b64_tr_b16 %0, %1 offset:" #OFF         \
               : "=v"(dst) : "v"(addr))

// ---------------- elementwise cast fp32 -> bf16 ----------------
__global__ void cast_src_k(const float* __restrict__ in, u16* __restrict__ outp, int n) {
  int i = (blockIdx.x * 256 + threadIdx.x) * 4;
  const int stride = gridDim.x * 256 * 4;
  for (; i < n; i += stride) {
    float4 v = *(const float4*)(in + i);
    u16x4 o; o[0] = f2bf(v.x); o[1] = f2bf(v.y); o[2] = f2bf(v.z); o[3] = f2bf(v.w);
    *(u16x4*)(outp + i) = o;
  }
}

// ---------------- transpose + cast: W (KxN f32) -> Wt (NxK bf16) ----------------
__global__ __launch_bounds__(256) void transpose_cast(const float* __restrict__ W,
                                                      u16* __restrict__ Wt, int K, int N) {
  __shared__ float t[32][33];
  const int n0 = blockIdx.x * 32, k0 = blockIdx.y * 32;
  const int tx = threadIdx.x & 31, ty = threadIdx.x >> 5;
#pragma unroll
  for (int i = 0; i < 4; i++) t[ty + i * 8][tx] = W[(size_t)(k0 + ty + i * 8) * N + n0 + tx];
  __syncthreads();
#pragma unroll
  for (int i = 0; i < 4; i++) Wt[(size_t)(n0 + ty + i * 8) * K + k0 + tx] = f2bf(t[tx][ty + i * 8]);
}

// ---------------- mask summary ----------------
__global__ void mask_init_k(int* flags) { if (threadIdx.x < 4) flags[threadIdx.x] = 1; }
__global__ void mask_check_k(const int* __restrict__ mask, int* __restrict__ flags, int n) {
  int i = blockIdx.x * 256 + threadIdx.x;
  const int st = gridDim.x * 256;
  for (; i < n; i += st) if (mask[i] == 0) flags[i >> 22] = 0;  // S*S = 2^22
}

// ---------------- 256^2 8-phase GEMM (T2+T3+T4+T5, + T1 swizzle) ----------------
template <int MODE, int TX, int TY, int NTX>
__global__ __launch_bounds__(512, 2) void gemm8p(const u16* __restrict__ A,
                                                 const u16* __restrict__ Bt,
                                                 const float* __restrict__ bias,
                                                 void* __restrict__ C,
                                                 int M, int N, int K) {
  __shared__ alignas(128) u16 lds[65536];
  const int tid = threadIdx.x, lane = tid & 63, w = tid >> 6;
  const int wm = w >> 2, wc = w & 3;
  const int frow = lane & 15, hi = lane >> 4;
  int bxs, bys;
  xcd_tile_remap<TX, TY, NTX>(blockIdx.y * gridDim.x + blockIdx.x, bxs, bys);
  const int bm = bys * 256, bn = bxs * 256;
  const int NT = K >> 6;

  const int cs = ((tid & 7) ^ ((tid >> 3) & 7)) * 8;
  const int sr = w * 8 + ((lane >> 3) & 7);
  const u16* Ab = A + (size_t)(bm + sr) * K + cs;
  const u16* Bbp = Bt + (size_t)(bn + sr) * K + cs;
  u16* lw = lds + w * 512;

  const int c0 = (hi * 8) ^ ((frow & 7) << 3);
  const u16* Abase = lds + wm * 8192 + frow * 64;
  const u16* Bbase = lds + 32768 + (wc >> 1) * 8192 + (wc & 1) * 4096 + frow * 64;

  f32x4 acc[8][4] = {};
  bf16x8 af0[4][2], af1[4][2], bf0[2][2], bf1[2][2];

#define STG(Pb, hh, kk, reg)                                                     \
  do {                                                                           \
    gload_lds16((Pb) + (size_t)((hh) * 128) * K + (kk), lw + (reg));             \
    gload_lds16((Pb) + (size_t)((hh) * 128 + 64) * K + (kk), lw + (reg) + 4096); \
  } while (0)
#define LDA(dst, sb, mh)                                                              \
  do {                                                                                \
    _Pragma("unroll") for (int m = 0; m < 4; m++) {                                   \
      dst[m][0] = *(const bf16x8*)(Abase + (sb) + ((mh) * 4 + m) * 1024 + c0);        \
      dst[m][1] = *(const bf16x8*)(Abase + (sb) + ((mh) * 4 + m) * 1024 + (c0 ^ 32)); \
    }                                                                                 \
  } while (0)
#define LDB(dst, sb, nh)                                                              \
  do {                                                                                \
    _Pragma("unroll") for (int n = 0; n < 2; n++) {                                   \
      dst[n][0] = *(const bf16x8*)(Bbase + (sb) + ((nh) * 2 + n) * 1024 + c0);        \
      dst[n][1] = *(const bf16x8*)(Bbase + (sb) + ((nh) * 2 + n) * 1024 + (c0 ^ 32)); \
    }                                                                                 \
  } while (0)
#define MM(AF, BF, mh, nh)                                                             \
  do {                                                                                 \
    __builtin_amdgcn_s_setprio(1);                                                     \
    _Pragma("unroll") for (int m = 0; m < 4; m++) _Pragma("unroll") for (int n = 0;    \
                                                                        n < 2; n++) { \
      acc[(mh)*4+m][(nh)*2+n] = mfma16(AF[m][0], BF[n][0], acc[(mh)*4+m][(nh)*2+n]);   \
      acc[(mh)*4+m][(nh)*2+n] = mfma16(AF[m][1], BF[n][1], acc[(mh)*4+m][(nh)*2+n]);   \
    }                                                                                  \
    __builtin_amdgcn_s_setprio(0);                                                     \
  } while (0)
#define BAR asm volatile("s_barrier" ::: "memory")
#define VMC(n) asm volatile("s_waitcnt vmcnt(" #n ")" ::: "memory")

  STG(Ab, 0, 0, 0);        STG(Ab, 1, 0, 8192);
  STG(Bbp, 0, 0, 32768);   STG(Bbp, 1, 0, 40960);
  STG(Ab, 0, 64, 16384);   STG(Ab, 1, 64, 24576);
  VMC(0);
  BAR;

  const int NI = NT >> 1;
#pragma unroll 1
  for (int i = 0; i < NI; ++i) {
    const int T = i * 2;
    const int kT1 = (T + 1) << 6;
    const int kT2 = (T + 2 < NT ? T + 2 : NT - 1) << 6;
    const int kT3 = (T + 3 < NT ? T + 3 : NT - 1) << 6;
    LDA(af0, 0, 0); LDB(bf0, 0, 0);
    STG(Bbp, 0, kT1, 49152);
    BAR; MM(af0, bf0, 0, 0); BAR;
    LDA(af1, 0, 1);
    STG(Bbp, 1, kT1, 57344);
    BAR; MM(af1, bf0, 1, 0); BAR;
    LDB(bf1, 0, 1);
    STG(Ab, 0, kT2, 0);
    BAR; MM(af0, bf1, 0, 1); BAR;
    STG(Ab, 1, kT2, 8192);
    VMC(4); BAR; MM(af1, bf1, 1, 1); BAR;
    LDA(af0, 16384, 0); LDB(bf0, 16384, 0);
    STG(Bbp, 0, kT2, 32768);
    BAR; MM(af0, bf0, 0, 0); BAR;
    LDA(af1, 16384, 1);
    STG(Bbp, 1, kT2, 40960);
    BAR; MM(af1, bf0, 1, 0); BAR;
    LDB(bf1, 16384, 1);
    STG(Ab, 0, kT3, 16384);
    BAR; MM(af0, bf1, 0, 1); BAR;
    STG(Ab, 1, kT3, 24576);
    VMC(4); BAR; MM(af1, bf1, 1, 1); BAR;
  }

#undef STG
#undef LDA
#undef LDB
#undef MM
#undef BAR
#undef VMC

#pragma unroll
  for (int m = 0; m < 8; m++) {
#pragma unroll
    for (int n = 0; n < 4; n++) {
      const int col = bn + wc * 64 + n * 16 + frow;
      const float bv = (MODE == 2) ? bias[col] : 0.f;
      const float sc = (MODE == 3 && col < Dd) ? QSCALE : 1.f;
#pragma unroll
      for (int r = 0; r < 4; r++) {
        const int row = bm + wm * 128 + m * 16 + hi * 4 + r;
        float v = acc[m][n][r];
        if (MODE == 2) v = fmaxf(v + bv, 0.f);
        if (MODE == 3) v *= sc;
        if (MODE == 0) ((float*)C)[(size_t)row * N + col] = v;
        else           ((u16*)C)[(size_t)row * N + col] = f2bf(v);
      }
    }
  }
}

// ---------------- 128x256 8-phase GEMM (+ T1 swizzle) ----------
template <int MODE, int TX, int TY, int NTX>
__global__ __launch_bounds__(512, 2) void gemm8ph(const u16* __restrict__ A,
                                                  const u16* __restrict__ Bt,
                                                  const float* __restrict__ bias,
                                                  void* __restrict__ C,
                                                  int M, int N, int K) {
  __shared__ alignas(128) u16 lds[49152];
  const int tid = threadIdx.x, lane = tid & 63, w = tid >> 6;
  const int wm = w >> 2, wc = w & 3;
  const int frow = lane & 15, hi = lane >> 4;
  int bxs, bys;
  xcd_tile_remap<TX, TY, NTX>(blockIdx.y * gridDim.x + blockIdx.x, bxs, bys);
  const int bm = bys * 128, bn = bxs * 256;
  const int NT = K >> 6;

  const int cs = ((tid & 7) ^ ((tid >> 3) & 7)) * 8;
  const int sr = w * 8 + ((lane >> 3) & 7);
  const u16* Ab = A + (size_t)(bm + sr) * K + cs;
  const u16* Bbp = Bt + (size_t)(bn + sr) * K + cs;
  u16* lwA = lds + w * 512;
  u16* lwB = lds + 16384 + w * 512;

  const int c0 = (hi * 8) ^ ((frow & 7) << 3);
  const u16* Abase = lds + wm * 4096 + frow * 64;
  const u16* Bbase = lds + 16384 + wc * 4096 + frow * 64;

  f32x4 acc[4][4] = {};
  bf16x8 af0[2][2], af1[2][2], bf0[2][2], bf1[2][2];

#define STGA(kk, reg)                                              \
  do {                                                             \
    gload_lds16(Ab + (kk), lwA + (reg));                           \
    gload_lds16(Ab + (size_t)64 * K + (kk), lwA + (reg) + 4096);   \
  } while (0)
#define STGB(hh, kk, reg)                                                            \
  do {                                                                               \
    gload_lds16(Bbp + (size_t)((hh) * 128) * K + (kk), lwB + (reg) + (hh) * 8192);   \
    gload_lds16(Bbp + (size_t)((hh) * 128 + 64) * K + (kk),                          \
                lwB + (reg) + (hh) * 8192 + 4096);                                   \
  } while (0)
#define LDA2(dst, sb, mh)                                                             \
  do {                                                                                \
    _Pragma("unroll") for (int m = 0; m < 2; m++) {                                   \
      dst[m][0] = *(const bf16x8*)(Abase + (sb) + ((mh) * 2 + m) * 1024 + c0);        \
      dst[m][1] = *(const bf16x8*)(Abase + (sb) + ((mh) * 2 + m) * 1024 + (c0 ^ 32)); \
    }                                                                                 \
  } while (0)
#define LDB2(dst, sb, nh)                                                             \
  do {                                                                                \
    _Pragma("unroll") for (int n = 0; n < 2; n++) {                                   \
      dst[n][0] = *(const bf16x8*)(Bbase + (sb) + ((nh) * 2 + n) * 1024 + c0);        \
      dst[n][1] = *(const bf16x8*)(Bbase + (sb) + ((nh) * 2 + n) * 1024 + (c0 ^ 32)); \
    }                                                                                 \
  } while (0)
#define MM2(AF, BF, mh, nh)                                                            \
  do {                                                                                 \
    __builtin_amdgcn_s_setprio(1);                                                     \
    _Pragma("unroll") for (int m = 0; m < 2; m++) _Pragma("unroll") for (int n = 0;    \
                                                                        n < 2; n++) { \
      acc[(mh)*2+m][(nh)*2+n] = mfma16(AF[m][0], BF[n][0], acc[(mh)*2+m][(nh)*2+n]);   \
      acc[(mh)*2+m][(nh)*2+n] = mfma16(AF[m][1], BF[n][1], acc[(mh)*2+m][(nh)*2+n]);   \
    }                                                                                  \
    __builtin_amdgcn_s_setprio(0);                                                     \
  } while (0)
#define BAR asm volatile("s_barrier" ::: "memory")
#define VMC(n) asm volatile("s_waitcnt vmcnt(" #n ")" ::: "memory")

  STGA(0, 0);
  STGB(0, 0, 0); STGB(1, 0, 0);
  STGA(64, 8192);
  VMC(0);
  BAR;

  const int NI = NT >> 1;
#pragma unroll 1
  for (int i = 0; i < NI; ++i) {
    const int T = i * 2;
    const int kT1 = (T + 1) << 6;
    const int kT2 = (T + 2 < NT ? T + 2 : NT - 1) << 6;
    const int kT3 = (T + 3 < NT ? T + 3 : NT - 1) << 6;
    LDA2(af0, 0, 0); LDB2(bf0, 0, 0);
    STGB(0, kT1, 16384);
    BAR; MM2(af0, bf0, 0, 0); BAR;
    LDA2(af1, 0, 1);
    STGB(1, kT1, 16384);
    BAR; MM2(af1, bf0, 1, 0); BAR;
    LDB2(bf1, 0, 1);
    STGA(kT2, 0);
    BAR; MM2(af0, bf1, 0, 1); BAR;
    VMC(2); BAR; MM2(af1, bf1, 1, 1); BAR;
    LDA2(af0, 8192, 0); LDB2(bf0, 16384, 0);
    STGB(0, kT2, 0);
    BAR; MM2(af0, bf0, 0, 0); BAR;
    LDA2(af1, 8192, 1);
    STGB(1, kT2, 0);
    BAR; MM2(af1, bf0, 1, 0); BAR;
    LDB2(bf1, 16384, 1);
    STGA(kT3, 8192);
    BAR; MM2(af0, bf1, 0, 1); BAR;
    VMC(2); BAR; MM2(af1, bf1, 1, 1); BAR;
  }

#undef STGA
#undef STGB
#undef LDA2
#undef LDB2
#undef MM2
#undef BAR
#undef VMC

#pragma unroll
  for (int m = 0; m < 4; m++) {
#pragma unroll
    for (int n = 0; n < 4; n++) {
      const int col = bn + wc * 64 + n * 16 + frow;
      const float bv = (MODE == 2) ? bias[col] : 0.f;
      const float sc = (MODE == 3 && col < Dd) ? QSCALE : 1.f;
#pragma unroll
      for (int r = 0; r < 4; r++) {
        const int row = bm + wm * 64 + m * 16 + hi * 4 + r;
        float v = acc[m][n][r];
        if (MODE == 2) v = fmaxf(v + bv, 0.f);
        if (MODE == 3) v *= sc;
        if (MODE == 0) ((float*)C)[(size_t)row * N + col] = v;
        else           ((u16*)C)[(size_t)row * N + col] = f2bf(v);
      }
    }
  }
}

// ---------------- fused flash attention ----------------
// R6: P never touches LDS. After swapped QK^T, lane (q=frow,hi) holds
// P[k=n*16+hi*4+r][q]; cvt_pk packs pw[n][b]; PV A-fragment word w of ks comes
// from lane frow+16*(2(hi&1)+(w>>1)), word pw[2ks+(hi>>1)][w&1] -> 8 ds_bpermute
// + 4 cndmask per ks. Frees Pl (9.2KB): LDS = 32KB exactly -> 5 blocks/CU.
__global__ __launch_bounds__(256, 5) void attn_fwd(const u16* __restrict__ qkv,
                                                   const int* __restrict__ mask,
                                                   const int* __restrict__ mflag,
                                                   u16* __restrict__ outb) {
  __shared__ alignas(128) u16 Ks[2 * 4096];
  __shared__ alignas(128) u16 Vs[2 * 4096];

  const int id = blockIdx.x;
  const int bx = (id & 7) * 256 + (id >> 3);  // T1: 8 XCD groups of 256
  const int qt = bx & 31;
  const int h = (bx >> 5) & 15;
  const int b = bx >> 9;
  const int tid = threadIdx.x;
  const int lane = tid & 63;
  const int w = tid >> 6;
  const int frow = lane & 15, hi = lane >> 4;
  const int qbase = qt * 64 + w * 16;

  bf16x8 qf[2];
  {
    const u16* qp = qkv + (size_t)(b * Ss + qbase + frow) * 3072 + h * 64 + hi * 8;
    qf[0] = *(const bf16x8*)(qp);
    qf[1] = *(const bf16x8*)(qp + 32);
  }
  const int allones = mflag[b];

  f32x4 oacc[4] = {};
  float mrow = -1e30f, lrow = 0.f;

  const size_t kvb = (size_t)(b * Ss) * 3072 + 1024 + h * 64;
  const int kcol_s = tid >> 2;
  const int dsw = ((tid & 3) ^ (kcol_s & 3)) * 8;
  const u16* Kg0 = qkv + kvb + (size_t)kcol_s * 3072 + dsw;
  const u16* Kg1 = Kg0 + 32;
  int kV0, dkV0, kV1, dkV1;
  {
    int p = tid, T = p >> 3, j = (p >> 1) & 3, hh = p & 1;
    kV0 = ((T >> 3) & 1) * 32 + (T & 3) * 8 + ((T >> 2) & 1) * 4 + j;
    dkV0 = ((T >> 4) & 3) * 16 + hh * 8;
    p = tid + 256; T = p >> 3; j = (p >> 1) & 3; hh = p & 1;
    kV1 = ((T >> 3) & 1) * 32 + (T & 3) * 8 + ((T >> 2) & 1) * 4 + j;
    dkV1 = ((T >> 4) & 3) * 16 + hh * 8;
  }
  const u16* Vg0 = qkv + kvb + 1024 + (size_t)kV0 * 3072 + dkV0;
  const u16* Vg1 = qkv + kvb + 1024 + (size_t)kV1 * 3072 + dkV1;

  const unsigned vbase = lds_addr(Vs) + lane * 8;
  // bpermute lane indices (bytes): L0 = frow + 32*(hi&1); L1 = L0 + 16
  const int idxA = (frow + ((hi & 1) << 5)) << 2;
  const int idxB = idxA + 64;
  const bool hiLow = hi < 2;

  gload_lds16(Kg0, Ks + w * 512);
  gload_lds16(Kg1, Ks + 2048 + w * 512);
  gload_lds16(Vg0, Vs + w * 512);
  gload_lds16(Vg1, Vs + 2048 + w * 512);
  __syncthreads();

#pragma unroll 1
  for (int kt = 0; kt < 32; kt++) {
    const int cur = kt & 1;
    if (kt < 31) {
      const size_t soff = (size_t)(kt + 1) * 64 * 3072;
      u16* Kb = Ks + (cur ^ 1) * 4096;
      u16* Vb = Vs + (cur ^ 1) * 4096;
      gload_lds16(Kg0 + soff, Kb + w * 512);
      gload_lds16(Kg1 + soff, Kb + 2048 + w * 512);
      gload_lds16(Vg0 + soff, Vb + w * 512);
      gload_lds16(Vg1 + soff, Vb + 2048 + w * 512);
    }
    const u16* Kbuf = Ks + cur * 4096;

    f32x4 sacc[4] = {};
    const int kswz = (hi ^ (frow & 3)) * 8;
#pragma unroll
    for (int ks = 0; ks < 2; ks++)
#pragma unroll
      for (int n = 0; n < 4; n++) {
        bf16x8 kf = *(const bf16x8*)&Kbuf[ks * 2048 + (n * 16 + frow) * 32 + kswz];
        sacc[n] = mfma16(kf, qf[ks], sacc[n]);
      }

    const int srow = kt * 64;
    float sv[16];
#pragma unroll
    for (int n = 0; n < 4; n++)
#pragma unroll
      for (int r = 0; r < 4; r++) {
        float s = sacc[n][r];  // already in log2 units (QSCALE folded)
        if (!allones) {
          const int qq = b * Ss + qbase + frow;
          const int kk = srow + n * 16 + hi * 4 + r;
          if (mask[(size_t)qq * Ss + kk] == 0) s = -1e30f;
        }
        sv[n * 4 + r] = s;
      }
    // depth-4 tree max + 2 shuffles
    float mA = fmaxf(fmaxf(fmaxf(sv[0], sv[1]), fmaxf(sv[2], sv[3])),
                     fmaxf(fmaxf(sv[4], sv[5]), fmaxf(sv[6], sv[7])));
    float mB = fmaxf(fmaxf(fmaxf(sv[8], sv[9]), fmaxf(sv[10], sv[11])),
                     fmaxf(fmaxf(sv[12], sv[13]), fmaxf(sv[14], sv[15])));
    float mt = fmaxf(mA, mB);
    mt = fmaxf(mt, __shfl_xor(mt, 16));
    mt = fmaxf(mt, __shfl_xor(mt, 32));
    if (__any(mt > mrow + 8.f)) {
      const float mn = fmaxf(mrow, mt);
      const float al = exp2f(mrow - mn);
      mrow = mn;
      lrow *= al;
      float alr[4];
#pragma unroll
      for (int r = 0; r < 4; r++) alr[r] = __shfl(al, (lane & 48) | (hi * 4 + r));
#pragma unroll
      for (int n = 0; n < 4; n++) {
        oacc[n][0] *= alr[0]; oacc[n][1] *= alr[1];
        oacc[n][2] *= alr[2]; oacc[n][3] *= alr[3];
      }
    }
    float ps[16];
#pragma unroll
    for (int i = 0; i < 16; i++) ps[i] = exp2f(sv[i] - mrow);
    // depth-4 tree sum
    float sA = ((ps[0] + ps[1]) + (ps[2] + ps[3])) + ((ps[4] + ps[5]) + (ps[6] + ps[7]));
    float sB = ((ps[8] + ps[9]) + (ps[10] + ps[11])) + ((ps[12] + ps[13]) + (ps[14] + ps[15]));
    float rs = sA + sB;
    rs += __shfl_xor(rs, 16);
    rs += __shfl_xor(rs, 32);
    lrow += rs;
    // pack P in-register: pw[n][b] = bf16(ps[4n+2b]), bf16(ps[4n+2b+1])
    unsigned pw[4][2];
#pragma unroll
    for (int n = 0; n < 4; n++) {
      pw[n][0] = cvtpk(ps[n * 4 + 0], ps[n * 4 + 1]);
      pw[n][1] = cvtpk(ps[n * 4 + 2], ps[n * 4 + 3]);
    }

    const unsigned vaddr = vbase + (cur << 13);
    u16x4 t0, t1, t2, t3, t4, t5, t6, t7;
#pragma unroll
    for (int ks = 0; ks < 2; ks++) {
      if (ks == 0) {
        TRRD(t0, vaddr, 0);    TRRD(t1, vaddr, 512);
        TRRD(t2, vaddr, 2048); TRRD(t3, vaddr, 2560);
        TRRD(t4, vaddr, 4096); TRRD(t5, vaddr, 4608);
        TRRD(t6, vaddr, 6144); TRRD(t7, vaddr, 6656);
      } else {
        TRRD(t0, vaddr, 1024); TRRD(t1, vaddr, 1536);
        TRRD(t2, vaddr, 3072); TRRD(t3, vaddr, 3584);
        TRRD(t4, vaddr, 5120); TRRD(t5, vaddr, 5632);
        TRRD(t6, vaddr, 7168); TRRD(t7, vaddr, 7680);
      }
      // in-register P redistribution (T12): 8 bpermute + 4 selects
      const unsigned sa0 = pw[2 * ks][0], sa1 = pw[2 * ks][1];
      const unsigned sb0 = pw[2 * ks + 1][0], sb1 = pw[2 * ks + 1][1];
      const unsigned a0 = __builtin_amdgcn_ds_bpermute(idxA, sa0);
      const unsigned b0 = __builtin_amdgcn_ds_bpermute(idxA, sb0);
      const unsigned a1 = __builtin_amdgcn_ds_bpermute(idxA, sa1);
      const unsigned b1 = __builtin_amdgcn_ds_bpermute(idxA, sb1);
      const unsigned a2 = __builtin_amdgcn_ds_bpermute(idxB, sa0);
      const unsigned b2 = __builtin_amdgcn_ds_bpermute(idxB, sb0);
      const unsigned a3 = __builtin_amdgcn_ds_bpermute(idxB, sa1);
      const unsigned b3 = __builtin_amdgcn_ds_bpermute(idxB, sb1);
      asm volatile("s_waitcnt lgkmcnt(0)" ::: "memory");
      __builtin_amdgcn_sched_barrier(0);
      union { unsigned u[4]; bf16x8 v; } pu;
      pu.u[0] = hiLow ? a0 : b0;
      pu.u[1] = hiLow ? a1 : b1;
      pu.u[2] = hiLow ? a2 : b2;
      pu.u[3] = hiLow ? a3 : b3;
      const bf16x8 pa = pu.v;
      oacc[0] = mfma16(pa, cat8(t0, t1), oacc[0]);
      oacc[1] = mfma16(pa, cat8(t2, t3), oacc[1]);
      oacc[2] = mfma16(pa, cat8(t4, t5), oacc[2]);
      oacc[3] = mfma16(pa, cat8(t6, t7), oacc[3]);
    }
    __syncthreads();
  }

  float lr[4];
#pragma unroll
  for (int r = 0; r < 4; r++) lr[r] = __shfl(lrow, (lane & 48) | (hi * 4 + r));
#pragma unroll
  for (int n = 0; n < 4; n++)
#pragma unroll
    for (int r = 0; r < 4; r++) {
      const int q = qbase + hi * 4 + r;
      const int dk = n * 16 + frow;
      outb[(size_t)(b * Ss + q) * 1024 + h * 64 + dk] = f2bf(oacc[n][r] / lr[r]);
    }
}

// ---------------- fused residual + bias + LayerNorm ----------------
__global__ __launch_bounds__(256) void ln_fuse(const float* __restrict__ a,
                                               const float* __restrict__ c,
                                               const float* __restrict__ bias,
                                               const float* __restrict__ g,
                                               const float* __restrict__ be,
                                               float* __restrict__ of,
                                               u16* __restrict__ ob) {
  __shared__ float red[4];
  const int tid = threadIdx.x;
  const size_t base = (size_t)blockIdx.x * 1024 + tid * 4;
  float4 va = *(const float4*)(a + base);
  float4 vc = *(const float4*)(c + base);
  float4 vb = *(const float4*)(bias + tid * 4);
  const float s0 = va.x + vc.x + vb.x, s1 = va.y + vc.y + vb.y;
  const float s2 = va.z + vc.z + vb.z, s3 = va.w + vc.w + vb.w;
  float sum = s0 + s1 + s2 + s3;
#pragma unroll
  for (int o = 32; o; o >>= 1) sum += __shfl_xor(sum, o);
  if ((tid & 63) == 0) red[tid >> 6] = sum;
  __syncthreads();
  const float mu = (red[0] + red[1] + red[2] + red[3]) * (1.f / 1024.f);
  __syncthreads();
  const float d0 = s0 - mu, d1 = s1 - mu, d2 = s2 - mu, d3 = s3 - mu;
  float vs = d0 * d0 + d1 * d1 + d2 * d2 + d3 * d3;
#pragma unroll
  for (int o = 32; o; o >>= 1) vs += __shfl_xor(vs, o);
  if ((tid & 63) == 0) red[tid >> 6] = vs;
  __syncthreads();
  const float var = (red[0] + red[1] + red[2] + red[3]) * (1.f / 1024.f);
  const float rs = rsqrtf(var + 1e-5f);
  float4 vg = *(const float4*)(g + tid * 4);
  float4 ve = *(const float4*)(be + tid * 4);
  const float y0 = d0 * rs * vg.x + ve.x, y1 = d1 * rs * vg.y + ve.y;
  const float y2 = d2 * rs * vg.z + ve.z, y3 = d3 * rs * vg.w + ve.w;
  if (of) { float4 y; y.x = y0; y.y = y1; y.z = y2; y.w = y3; *(float4*)(of + base) = y; }
  if (ob) { u16x4 o; o[0] = f2bf(y0); o[1] = f2bf(y1); o[2] = f2bf(y2); o[3] = f2bf(y3);
            *(u16x4*)(ob + base) = o; }
}

extern "C" void kernel_launch(void* const* d_in, const int* in_sizes, int n_in,
                              void* d_out, int out_size, void* d_ws, size_t ws_size,
                              hipStream_t stream) {
  const float* src = (const float*)d_in[0];
  const int* mask = (const int*)d_in[1];
  const float* Wq = (const float*)d_in[2];
  const float* Wk = (const float*)d_in[3];
  const float* Wv = (const float*)d_in[4];
  const float* Wo = (const float*)d_in[5];
  const float* bo = (const float*)d_in[6];
  const float* g1 = (const float*)d_in[7];
  const float* be1 = (const float*)d_in[8];
  const float* W1 = (const float*)d_in[9];
  const float* b1 = (const float*)d_in[10];
  const float* W2 = (const float*)d_in[11];
  const float* b2 = (const float*)d_in[12];
  const float* g2 = (const float*)d_in[13];
  const float* be2 = (const float*)d_in[14];
  float* outp = (float*)d_out;
  (void)in_sizes; (void)n_in; (void)out_size; (void)ws_size;

  char* ws = (char*)d_ws;
  size_t off = 0;
  auto take = [&](size_t bytes) -> char* {
    char* p = ws + off;
    off = (off + bytes + 255) & ~(size_t)255;
    return p;
  };
  u16* srcb  = (u16*)take((size_t)BS * Dd * 2);
  u16* wqkvt = (u16*)take((size_t)3 * Dd * Dd * 2);
  u16* wot   = (u16*)take((size_t)Dd * Dd * 2);
  u16* w1t   = (u16*)take((size_t)Dd * DFF * 2);
  u16* w2t   = (u16*)take((size_t)DFF * Dd * 2);
  char* qkvr = take((size_t)BS * 3 * Dd * 2);
  u16* qkvb  = (u16*)qkvr;
  float* Cf  = (float*)qkvr;
  u16* attnb = (u16*)take((size_t)BS * Dd * 2);
  float* xf  = (float*)take((size_t)BS * Dd * 4);
  u16* hb    = (u16*)take((size_t)BS * DFF * 2);
  int* flags = (int*)take(256);

  cast_src_k<<<2048, 256, 0, stream>>>(src, srcb, BS * Dd);
  transpose_cast<<<dim3(32, 32), 256, 0, stream>>>(Wq, wqkvt,                Dd, Dd);
  transpose_cast<<<dim3(32, 32), 256, 0, stream>>>(Wk, wqkvt + Dd * Dd,      Dd, Dd);
  transpose_cast<<<dim3(32, 32), 256, 0, stream>>>(Wv, wqkvt + 2 * Dd * Dd,  Dd, Dd);
  transpose_cast<<<dim3(32, 32), 256, 0, stream>>>(Wo, wot, Dd, Dd);
  transpose_cast<<<dim3(128, 32), 256, 0, stream>>>(W1, w1t, Dd, DFF);
  transpose_cast<<<dim3(32, 128), 256, 0, stream>>>(W2, w2t, DFF, Dd);
  mask_init_k<<<1, 64, 0, stream>>>(flags);
  mask_check_k<<<2048, 256, 0, stream>>>(mask, flags, Bb * Ss * Ss);

  gemm8ph<3, 3, 8, 4><<<dim3(3 * Dd / 256, BS / 128), 512, 0, stream>>>(
      srcb, wqkvt, nullptr, qkvb, BS, 3 * Dd, Dd);
  attn_fwd<<<Bb * Hh * (Ss / 64), 256, 0, stream>>>(qkvb, mask, flags, attnb);
  gemm8ph<0, 4, 8, 1><<<dim3(Dd / 256, BS / 128), 512, 0, stream>>>(
      attnb, wot, nullptr, Cf, BS, Dd, Dd);
  ln_fuse<<<BS, 256, 0, stream>>>(src, Cf, bo, g1, be1, xf, attnb);
  gemm8p<2, 4, 4, 4><<<dim3(DFF / 256, BS / 256), 512, 0, stream>>>(
      attnb, w1t, b1, hb, BS, DFF, Dd);
  gemm8ph<0, 2, 2, 2><<<dim3(Dd / 256, BS / 128), 512, 0, stream>>>(
      hb, w2t, nullptr, Cf, BS, Dd, DFF);
  ln_fuse<<<BS, 256, 0, stream>>>(xf, Cf, b2, g2, be2, outp, nullptr);
}